// Round 1
// baseline (370.179 us; speedup 1.0000x reference)
//
#include <hip/hip_runtime.h>
#include <hip/hip_bf16.h>
#include <cstdint>
#include <cstddef>

#define TAU 1e-4f
#define LN_EPS 1e-5f

typedef unsigned short ushort_t;
typedef __attribute__((ext_vector_type(8))) short short8;
typedef __attribute__((ext_vector_type(4))) float f32x4;

__device__ __forceinline__ ushort_t f2bf(float f) {
    union { float f; unsigned int u; } c; c.f = f;
    unsigned int r = (c.u + 0x7fffu + ((c.u >> 16) & 1u)) >> 16;
    return (ushort_t)r;
}

__device__ __forceinline__ int eidx(int i, int j) {
    // edges (i,j), i<j, lexicographic. offset(i) = 15i - i(i-1)/2
    return i * 15 - (i * (i - 1)) / 2 + (j - i - 1);
}

// ---------------------------------------------------------------------------
// Weight prep: WcatT[n][j] bf16, j in [0,1536): j = s*256+q -> Wn_s[q,n]=sum_d Wv[q,s*256+d]*Wo[s*256+d,n]
//                                              j = 768+s*256+q -> We2_s[q,n] with Wo rows 768+...
// ---------------------------------------------------------------------------
__global__ __launch_bounds__(256) void kw_wcat(const float* __restrict__ Wv,
                                               const float* __restrict__ We,
                                               const float* __restrict__ Wo,
                                               ushort_t* __restrict__ WcatT) {
    __shared__ float rowS[256];
    const int j = blockIdx.x;
    const int n = threadIdx.x;
    const int half = j / 768;
    const int rem = j - half * 768;
    const int s = rem >> 8;
    const int q = rem & 255;
    const float* src = half ? We : Wv;
    rowS[n] = src[(size_t)q * 768 + s * 256 + n];
    __syncthreads();
    const float* wo = Wo + (size_t)(half * 768 + s * 256) * 256 + n;
    float acc = 0.f;
    for (int d = 0; d < 256; ++d) acc += rowS[d] * wo[(size_t)d * 256];
    WcatT[(size_t)n * 1536 + j] = f2bf(acc);
}

__global__ void kw_vec(const float* __restrict__ bv, const float* __restrict__ be,
                       const float* __restrict__ Wo, const float* __restrict__ bo,
                       float* __restrict__ cvec, float* __restrict__ beWo) {
    const int n = threadIdx.x;  // 256 threads
    float cv = bo[n];
    for (int s = 0; s < 3; ++s) {
        float a1 = 0.f, a2 = 0.f;
        for (int d = 0; d < 256; ++d) {
            a1 += bv[s * 256 + d] * Wo[(size_t)(s * 256 + d) * 256 + n];
            a2 += be[s * 256 + d] * Wo[(size_t)(768 + s * 256 + d) * 256 + n];
        }
        cv += TAU * a1;           // L0 @ 1 == tau exactly (Laplacian row sums vanish)
        beWo[s * 256 + n] = a2;
    }
    cvec[n] = cv;
}

__global__ void kw_tr1(const float* __restrict__ Wf1, ushort_t* __restrict__ Wf1T) {
    const int n = blockIdx.x;       // 0..1023
    const int k = threadIdx.x;      // 0..255
    Wf1T[(size_t)n * 256 + k] = f2bf(Wf1[(size_t)k * 1024 + n]);
}

__global__ void kw_tr2(const float* __restrict__ Wf2, ushort_t* __restrict__ Wf2T) {
    const int n = blockIdx.x;       // 0..255
    for (int k = threadIdx.x; k < 1024; k += 256)
        Wf2T[(size_t)n * 1024 + k] = f2bf(Wf2[(size_t)k * 256 + n]);
}

// ---------------------------------------------------------------------------
// K1: per-batch graph kernel. One block per b. fp32 throughout (precision-
// sensitive small algebra). Emits Mcat (B*16, 1536) bf16 and gbuf (B*16, 3).
// ---------------------------------------------------------------------------
__global__ __launch_bounds__(256) void k1_graph(
    const float* __restrict__ xg, const float* __restrict__ maskg,
    const float* __restrict__ Wg, const float* __restrict__ bg,
    const float* __restrict__ ls, const float* __restrict__ g1,
    const float* __restrict__ b1, ushort_t* __restrict__ Mcat,
    float* __restrict__ gbuf) {
    const int b = blockIdx.x;
    const int tid = threadIdx.x;
    __shared__ float xs[16][257];
    __shared__ float wgs[256 * 16];
    __shared__ float Pl[16][17];
    __shared__ float dotm[16][17];
    __shared__ float Dsq[16][17];
    __shared__ float W1s[120];
    __shared__ float A1[16][121];
    __shared__ float Gm[16][17];
    __shared__ float L0[16][17];
    __shared__ float gg[16];
    __shared__ float mk[16];
    __shared__ short eu_[120], ev_[120];

    const float* xb = xg + (size_t)b * 4096;
    for (int i = 0; i < 16; ++i) {
        int idx = tid + i * 256;
        xs[idx >> 8][idx & 255] = xb[idx];
    }
    for (int i = 0; i < 16; ++i) wgs[tid + i * 256] = Wg[tid + i * 256];
    if (tid < 16) mk[tid] = maskg[b * 16 + tid];
    if (tid < 120) {
        int rem = tid, i = 0;
        while (rem >= 15 - i) { rem -= 15 - i; ++i; }
        eu_[tid] = (short)i; ev_[tid] = (short)(i + 1 + rem);
    }
    __syncthreads();

    // LN1: thread (k, c) owns elements c+16j of row k
    {
        const int k = tid >> 4, c = tid & 15;
        float s = 0.f;
        for (int j = 0; j < 16; ++j) s += xs[k][c + 16 * j];
        for (int off = 8; off; off >>= 1) s += __shfl_down(s, off, 16);
        float mean = __shfl(s, 0, 16) * (1.f / 256.f);
        float vs = 0.f;
        for (int j = 0; j < 16; ++j) { float d = xs[k][c + 16 * j] - mean; vs += d * d; }
        for (int off = 8; off; off >>= 1) vs += __shfl_down(vs, off, 16);
        float rstd = rsqrtf(__shfl(vs, 0, 16) * (1.f / 256.f) + LN_EPS);
        for (int j = 0; j < 16; ++j) {
            int cc = c + 16 * j;
            xs[k][cc] = (xs[k][cc] - mean) * rstd * g1[cc] + b1[cc];
        }
    }
    __syncthreads();

    // P = xn @ Wg + bg
    {
        const int k = tid >> 4, c = tid & 15;
        float acc = bg[c];
        for (int q = 0; q < 256; ++q) acc += xs[k][q] * wgs[q * 16 + c];
        Pl[k][c] = acc;
    }
    __syncthreads();
    {
        const int k = tid >> 4, l = tid & 15;
        float d = 0.f;
        for (int c = 0; c < 16; ++c) d += Pl[k][c] * Pl[l][c];
        dotm[k][l] = d;
    }
    __syncthreads();
    {
        const int k = tid >> 4, l = tid & 15;
        float v = dotm[k][k] + dotm[l][l] - 2.f * dotm[k][l];
        Dsq[k][l] = fmaxf(v, 0.f) * mk[k] * mk[l];
    }

    for (int s = 0; s < 3; ++s) {
        __syncthreads();
        const float sig2 = expf(2.f * ls[s]);
        const float inv2 = 1.f / (2.f * sig2 + 1e-8f);
        if (tid < 120) {
            int u = eu_[tid], v = ev_[tid];
            W1s[tid] = expf(-Dsq[u][v] * inv2) * mk[u] * mk[v];
        }
        for (int idx = tid; idx < 16 * 121; idx += 256) ((float*)A1)[idx] = 0.f;
        __syncthreads();
        // triangle scatter: ABS@B2 column = 2*e_{mid}; signs (ij:+, ik:-, jk:+)
        for (int t = tid; t < 560; t += 256) {
            int rem = t, i = 0;
            while (rem >= ((15 - i) * (14 - i)) / 2) { rem -= ((15 - i) * (14 - i)) / 2; ++i; }
            int j = i + 1;
            while (rem >= 15 - j) { rem -= 15 - j; ++j; }
            int k3 = j + 1 + rem;
            int e_ij = eidx(i, j), e_ik = eidx(i, k3), e_jk = eidx(j, k3);
            float t2 = 2.f * W1s[e_ij] * W1s[e_jk] * W1s[e_ik];
            atomicAdd(&A1[j][e_ij], t2);
            atomicAdd(&A1[j][e_ik], -t2);
            atomicAdd(&A1[j][e_jk], t2);
        }
        __syncthreads();
        // ABS@term_down + tau*ABS, closed form via gamma[k,m]
        for (int idx = tid; idx < 1920; idx += 256) {
            int k = idx / 120, f = idx - k * 120;
            int u = eu_[f], v = ev_[f];
            float gu = (u == k) ? (float)(2 * k - 15) : ((u > k) ? 1.f : -1.f);
            float gv = (v == k) ? (float)(2 * k - 15) : ((v > k) ? 1.f : -1.f);
            float val = -gu * mk[u] + gv * mk[v];
            if (u == k || v == k) val += TAU;
            A1[k][f] += val;
        }
        __syncthreads();
        {
            const int k = tid >> 4, m = tid & 15;
            float sum = 0.f;
            for (int o = 0; o < 16; ++o) {
                if (o == m) continue;
                int f = (o < m) ? eidx(o, m) : eidx(m, o);
                sum += A1[k][f];
            }
            Gm[k][m] = sum;
            float l0;
            if (k == m) {
                float dsum = 0.f;
                for (int o = 0; o < 16; ++o)
                    if (o != k) dsum += W1s[(o < k) ? eidx(o, k) : eidx(k, o)];
                l0 = dsum + TAU;
            } else {
                l0 = -W1s[(k < m) ? eidx(k, m) : eidx(m, k)];
            }
            L0[k][m] = l0;
        }
        if (tid < 16) {
            float sum = 0.f;
            for (int f = 0; f < 120; ++f) sum += A1[tid][f];
            gg[tid] = sum;
        }
        __syncthreads();
        // H_s = L0@xn, Gx_s = G@xn -> Mcat rows (bf16)
        {
            const int q = tid;
            for (int k = 0; k < 16; ++k) {
                float hv = 0.f, gv = 0.f;
                for (int l = 0; l < 16; ++l) {
                    float xv = xs[l][q];
                    hv += L0[k][l] * xv;
                    gv += Gm[k][l] * xv;
                }
                size_t base = (size_t)(b * 16 + k) * 1536;
                Mcat[base + s * 256 + q] = f2bf(hv);
                Mcat[base + 768 + s * 256 + q] = f2bf(gv);
            }
        }
        if (tid < 16) gbuf[(size_t)(b * 16 + tid) * 3 + s] = gg[tid];
    }
}

// ---------------------------------------------------------------------------
// Shared MFMA GEMM core: BM=64, BN=256, BK=32, 4 waves, 64x64 wave-tiles.
// A: (M,K) bf16 row-major. Bt: (N,K) bf16 row-major (N-major = pre-transposed).
// ---------------------------------------------------------------------------
__device__ __forceinline__ void gemm_core(const ushort_t* __restrict__ A,
                                          const ushort_t* __restrict__ Bt,
                                          int Kdim, int m0, int n0,
                                          f32x4 acc[4][4],
                                          ushort_t (*As)[40], ushort_t (*Bs)[40]) {
    const int tid = threadIdx.x;
    const int wave = tid >> 6, lane = tid & 63;
    const int lq = lane >> 4, lr = lane & 15;
    const int r = tid >> 2, ca = (tid & 3) << 3;
    const ushort_t* Ag = A + (size_t)(m0 + r) * Kdim + ca;
    const ushort_t* Bg0 = Bt + (size_t)(n0 + r) * Kdim + ca;
    const ushort_t* Bg1 = Bt + (size_t)(n0 + 64 + r) * Kdim + ca;
    const ushort_t* Bg2 = Bt + (size_t)(n0 + 128 + r) * Kdim + ca;
    const ushort_t* Bg3 = Bt + (size_t)(n0 + 192 + r) * Kdim + ca;
    for (int kt = 0; kt < Kdim; kt += 32) {
        __syncthreads();
        *(uint4*)&As[r][ca] = *(const uint4*)(Ag + kt);
        *(uint4*)&Bs[r][ca] = *(const uint4*)(Bg0 + kt);
        *(uint4*)&Bs[64 + r][ca] = *(const uint4*)(Bg1 + kt);
        *(uint4*)&Bs[128 + r][ca] = *(const uint4*)(Bg2 + kt);
        *(uint4*)&Bs[192 + r][ca] = *(const uint4*)(Bg3 + kt);
        __syncthreads();
        short8 af[4], bfr[4];
#pragma unroll
        for (int i = 0; i < 4; ++i) af[i] = *(const short8*)&As[i * 16 + lr][lq * 8];
#pragma unroll
        for (int j = 0; j < 4; ++j) bfr[j] = *(const short8*)&Bs[wave * 64 + j * 16 + lr][lq * 8];
#pragma unroll
        for (int i = 0; i < 4; ++i)
#pragma unroll
            for (int j = 0; j < 4; ++j)
                acc[i][j] = __builtin_amdgcn_mfma_f32_16x16x32_bf16(af[i], bfr[j], acc[i][j], 0, 0, 0);
    }
}

// K2: Z = Mcat @ Wcat; epilogue x' = x + Z + cvec + sum_s g*beWo_s
__global__ __launch_bounds__(256) void k2_gemm(
    const ushort_t* __restrict__ Mcat, const ushort_t* __restrict__ WcatT,
    const float* __restrict__ xin, const float* __restrict__ cvec,
    const float* __restrict__ beWo, const float* __restrict__ gbuf,
    float* __restrict__ xp) {
    __shared__ ushort_t As[64][40];
    __shared__ ushort_t Bs[256][40];
    __shared__ float cvS[256], bewS[3][256], gblk[64][3];
    const int tid = threadIdx.x;
    const int m0 = blockIdx.x * 64;
    cvS[tid] = cvec[tid];
    bewS[0][tid] = beWo[tid];
    bewS[1][tid] = beWo[256 + tid];
    bewS[2][tid] = beWo[512 + tid];
    if (tid < 192) { int rr = tid / 3, s = tid - rr * 3; gblk[rr][s] = gbuf[(size_t)(m0 + rr) * 3 + s]; }
    f32x4 acc[4][4] = {};
    gemm_core(Mcat, WcatT, 1536, m0, 0, acc, As, Bs);
    const int wave = tid >> 6, lane = tid & 63, lq = lane >> 4, lr = lane & 15;
#pragma unroll
    for (int i = 0; i < 4; ++i)
#pragma unroll
        for (int j = 0; j < 4; ++j) {
            int n = wave * 64 + j * 16 + lr;
#pragma unroll
            for (int v = 0; v < 4; ++v) {
                int rl = i * 16 + lq * 4 + v;
                size_t idx = (size_t)(m0 + rl) * 256 + n;
                float z = acc[i][j][v] + xin[idx] + cvS[n] + gblk[rl][0] * bewS[0][n] +
                          gblk[rl][1] * bewS[1][n] + gblk[rl][2] * bewS[2][n];
                xp[idx] = z;
            }
        }
}

// LN2 -> h (bf16)
__global__ __launch_bounds__(256) void k_ln2(const float* __restrict__ xp,
                                             const float* __restrict__ g2,
                                             const float* __restrict__ b2,
                                             ushort_t* __restrict__ h) {
    const int tid = threadIdx.x;
    const int row = blockIdx.x * 4 + (tid >> 6);
    const int lane = tid & 63;
    const float* xr = xp + (size_t)row * 256;
    float v0 = xr[lane], v1 = xr[lane + 64], v2 = xr[lane + 128], v3 = xr[lane + 192];
    float s = v0 + v1 + v2 + v3;
    for (int m = 32; m; m >>= 1) s += __shfl_xor(s, m, 64);
    float mean = s * (1.f / 256.f);
    float d0 = v0 - mean, d1 = v1 - mean, d2 = v2 - mean, d3 = v3 - mean;
    float q = d0 * d0 + d1 * d1 + d2 * d2 + d3 * d3;
    for (int m = 32; m; m >>= 1) q += __shfl_xor(q, m, 64);
    float rstd = rsqrtf(q * (1.f / 256.f) + LN_EPS);
    ushort_t* hr = h + (size_t)row * 256;
    hr[lane] = f2bf(d0 * rstd * g2[lane] + b2[lane]);
    hr[lane + 64] = f2bf(d1 * rstd * g2[lane + 64] + b2[lane + 64]);
    hr[lane + 128] = f2bf(d2 * rstd * g2[lane + 128] + b2[lane + 128]);
    hr[lane + 192] = f2bf(d3 * rstd * g2[lane + 192] + b2[lane + 192]);
}

// K3: F1g = gelu(h @ Wf1 + bf1) bf16
__global__ __launch_bounds__(256) void k3_gemm(const ushort_t* __restrict__ h,
                                               const ushort_t* __restrict__ Wf1T,
                                               const float* __restrict__ bf1,
                                               ushort_t* __restrict__ F1g) {
    __shared__ ushort_t As[64][40];
    __shared__ ushort_t Bs[256][40];
    const int tid = threadIdx.x;
    const int m0 = (blockIdx.x >> 2) * 64;
    const int n0 = (blockIdx.x & 3) * 256;
    f32x4 acc[4][4] = {};
    gemm_core(h, Wf1T, 256, m0, n0, acc, As, Bs);
    const int wave = tid >> 6, lane = tid & 63, lq = lane >> 4, lr = lane & 15;
#pragma unroll
    for (int i = 0; i < 4; ++i)
#pragma unroll
        for (int j = 0; j < 4; ++j) {
            int n = n0 + wave * 64 + j * 16 + lr;
#pragma unroll
            for (int v = 0; v < 4; ++v) {
                int rg = m0 + i * 16 + lq * 4 + v;
                float u = acc[i][j][v] + bf1[n];
                float gl = 0.5f * u * (1.f + erff(u * 0.70710678118f));
                F1g[(size_t)rg * 1024 + n] = f2bf(gl);
            }
        }
}

// K4: out = x' + F1g @ Wf2 + bf2
__global__ __launch_bounds__(256) void k4_gemm(const ushort_t* __restrict__ F1g,
                                               const ushort_t* __restrict__ Wf2T,
                                               const float* __restrict__ bf2,
                                               const float* __restrict__ xp,
                                               float* __restrict__ out) {
    __shared__ ushort_t As[64][40];
    __shared__ ushort_t Bs[256][40];
    const int tid = threadIdx.x;
    const int m0 = blockIdx.x * 64;
    f32x4 acc[4][4] = {};
    gemm_core(F1g, Wf2T, 1024, m0, 0, acc, As, Bs);
    const int wave = tid >> 6, lane = tid & 63, lq = lane >> 4, lr = lane & 15;
#pragma unroll
    for (int i = 0; i < 4; ++i)
#pragma unroll
        for (int j = 0; j < 4; ++j) {
            int n = wave * 64 + j * 16 + lr;
#pragma unroll
            for (int v = 0; v < 4; ++v) {
                size_t idx = (size_t)(m0 + i * 16 + lq * 4 + v) * 256 + n;
                out[idx] = xp[idx] + acc[i][j][v] + bf2[n];
            }
        }
}

extern "C" void kernel_launch(void* const* d_in, const int* in_sizes, int n_in,
                              void* d_out, int out_size, void* d_ws, size_t ws_size,
                              hipStream_t stream) {
    const float* x = (const float*)d_in[0];
    const float* mask = (const float*)d_in[1];
    const float* Wg = (const float*)d_in[2];
    const float* bg = (const float*)d_in[3];
    const float* ls = (const float*)d_in[4];
    const float* Wv = (const float*)d_in[5];
    const float* bv = (const float*)d_in[6];
    const float* We = (const float*)d_in[7];
    const float* be = (const float*)d_in[8];
    const float* Wo = (const float*)d_in[9];
    const float* bo = (const float*)d_in[10];
    const float* g1 = (const float*)d_in[11];
    const float* b1 = (const float*)d_in[12];
    const float* g2 = (const float*)d_in[13];
    const float* b2 = (const float*)d_in[14];
    const float* Wf1 = (const float*)d_in[15];
    const float* bf1 = (const float*)d_in[16];
    const float* Wf2 = (const float*)d_in[17];
    const float* bf2 = (const float*)d_in[18];
    float* out = (float*)d_out;

    char* ws = (char*)d_ws;
    ushort_t* Mcat = (ushort_t*)(ws);                   // 50,331,648 B
    ushort_t* WcatT = (ushort_t*)(ws + 50331648);       //    786,432
    ushort_t* Wf1T = (ushort_t*)(ws + 51118080);        //    524,288
    ushort_t* Wf2T = (ushort_t*)(ws + 51642368);        //    524,288
    float* cvec = (float*)(ws + 52166656);              //      1,024
    float* beWo = (float*)(ws + 52167680);              //      3,072
    float* gbuf = (float*)(ws + 52170752);              //    196,608
    float* xp = (float*)(ws + 52367360);                // 16,777,216
    ushort_t* h = (ushort_t*)(ws + 69144576);           //  8,388,608
    ushort_t* F1g = (ushort_t*)(ws + 77533184);         // 33,554,432  (total ~111 MB)

    kw_wcat<<<dim3(1536), dim3(256), 0, stream>>>(Wv, We, Wo, WcatT);
    kw_vec<<<dim3(1), dim3(256), 0, stream>>>(bv, be, Wo, bo, cvec, beWo);
    kw_tr1<<<dim3(1024), dim3(256), 0, stream>>>(Wf1, Wf1T);
    kw_tr2<<<dim3(256), dim3(256), 0, stream>>>(Wf2, Wf2T);
    k1_graph<<<dim3(1024), dim3(256), 0, stream>>>(x, mask, Wg, bg, ls, g1, b1, Mcat, gbuf);
    k2_gemm<<<dim3(256), dim3(256), 0, stream>>>(Mcat, WcatT, x, cvec, beWo, gbuf, xp);
    k_ln2<<<dim3(4096), dim3(256), 0, stream>>>(xp, g2, b2, h);
    k3_gemm<<<dim3(1024), dim3(256), 0, stream>>>(h, Wf1T, bf1, F1g);
    k4_gemm<<<dim3(256), dim3(256), 0, stream>>>(F1g, Wf2T, bf2, xp, out);
}

// Round 2
// 318.651 us; speedup vs baseline: 1.1617x; 1.1617x over previous
//
#include <hip/hip_runtime.h>
#include <hip/hip_bf16.h>
#include <cstdint>
#include <cstddef>

#define TAU 1e-4f
#define LN_EPS 1e-5f

typedef unsigned short ushort_t;
typedef __attribute__((ext_vector_type(8))) short short8;
typedef __attribute__((ext_vector_type(4))) float f32x4;

__device__ __forceinline__ ushort_t f2bf(float f) {
    union { float f; unsigned int u; } c; c.f = f;
    unsigned int r = (c.u + 0x7fffu + ((c.u >> 16) & 1u)) >> 16;
    return (ushort_t)r;
}
__device__ __forceinline__ float bf2f(ushort_t u) {
    union { unsigned int u; float f; } c; c.u = ((unsigned int)u) << 16;
    return c.f;
}

__device__ __forceinline__ int eidx(int i, int j) {
    return i * 15 - (i * (i - 1)) / 2 + (j - i - 1);
}

// async global->LDS, 16B per lane. LDS dest = wave-uniform base + lane*16.
__device__ __forceinline__ void glds16(const void* g, void* l) {
    __builtin_amdgcn_global_load_lds((const __attribute__((address_space(1))) unsigned int*)g,
                                     (__attribute__((address_space(3))) unsigned int*)l,
                                     16, 0, 0);
}

// ---------------------------------------------------------------------------
// Weight prep
// ---------------------------------------------------------------------------
__global__ __launch_bounds__(256) void kw_wcat(const float* __restrict__ Wv,
                                               const float* __restrict__ We,
                                               const float* __restrict__ Wo,
                                               ushort_t* __restrict__ WcatT) {
    __shared__ float rowS[256];
    const int j = blockIdx.x;
    const int n = threadIdx.x;
    const int half = j / 768;
    const int rem = j - half * 768;
    const int s = rem >> 8;
    const int q = rem & 255;
    const float* src = half ? We : Wv;
    rowS[n] = src[(size_t)q * 768 + s * 256 + n];
    __syncthreads();
    const float* wo = Wo + (size_t)(half * 768 + s * 256) * 256 + n;
    float acc = 0.f;
    for (int d = 0; d < 256; ++d) acc += rowS[d] * wo[(size_t)d * 256];
    WcatT[(size_t)n * 1536 + j] = f2bf(acc);
}

__global__ void kw_vec(const float* __restrict__ bv, const float* __restrict__ be,
                       const float* __restrict__ Wo, const float* __restrict__ bo,
                       float* __restrict__ cvec, float* __restrict__ beWo) {
    const int n = threadIdx.x;
    float cv = bo[n];
    for (int s = 0; s < 3; ++s) {
        float a1 = 0.f, a2 = 0.f;
        for (int d = 0; d < 256; ++d) {
            a1 += bv[s * 256 + d] * Wo[(size_t)(s * 256 + d) * 256 + n];
            a2 += be[s * 256 + d] * Wo[(size_t)(768 + s * 256 + d) * 256 + n];
        }
        cv += TAU * a1;
        beWo[s * 256 + n] = a2;
    }
    cvec[n] = cv;
}

__global__ void kw_tr1(const float* __restrict__ Wf1, ushort_t* __restrict__ Wf1T) {
    const int n = blockIdx.x;
    const int k = threadIdx.x;
    Wf1T[(size_t)n * 256 + k] = f2bf(Wf1[(size_t)k * 1024 + n]);
}

__global__ void kw_tr2(const float* __restrict__ Wf2, ushort_t* __restrict__ Wf2T) {
    const int n = blockIdx.x;
    for (int k = threadIdx.x; k < 1024; k += 256)
        Wf2T[(size_t)n * 1024 + k] = f2bf(Wf2[(size_t)k * 256 + n]);
}

// ---------------------------------------------------------------------------
// K1a: per-b graph algebra. Outputs xn (bf16), Mbuf (96x16 fp32 per b), gbuf.
// ---------------------------------------------------------------------------
__global__ __launch_bounds__(256) void k1a_graph(
    const float* __restrict__ xg, const float* __restrict__ maskg,
    const float* __restrict__ Wg, const float* __restrict__ bg,
    const float* __restrict__ ls, const float* __restrict__ g1,
    const float* __restrict__ b1, ushort_t* __restrict__ xnbuf,
    float* __restrict__ Mbuf, float* __restrict__ gbuf) {
    const int b = blockIdx.x;
    const int tid = threadIdx.x;
    __shared__ float xs[16][257];
    __shared__ float Pl[16][17];
    __shared__ float dotm[16][17];
    __shared__ float Dsq[16][17];
    __shared__ float W1s[120];
    __shared__ float A1[16][121];
    __shared__ float mk[16];
    __shared__ short eu_[120], ev_[120];
    __shared__ short te1[560], te2[560], te3[560], tj_[560];

    const float* xb = xg + (size_t)b * 4096;
    for (int i = 0; i < 16; ++i) {
        int idx = tid + i * 256;
        xs[idx >> 8][idx & 255] = xb[idx];
    }
    if (tid < 16) mk[tid] = maskg[b * 16 + tid];
    if (tid < 120) {
        int rem = tid, i = 0;
        while (rem >= 15 - i) { rem -= 15 - i; ++i; }
        eu_[tid] = (short)i; ev_[tid] = (short)(i + 1 + rem);
    }
    // triangle tables (hoisted out of s-loop)
    for (int t = tid; t < 560; t += 256) {
        int rem = t, i = 0;
        while (rem >= ((15 - i) * (14 - i)) / 2) { rem -= ((15 - i) * (14 - i)) / 2; ++i; }
        int j = i + 1;
        while (rem >= 15 - j) { rem -= 15 - j; ++j; }
        int k3 = j + 1 + rem;
        te1[t] = (short)eidx(i, j);
        te2[t] = (short)eidx(i, k3);
        te3[t] = (short)eidx(j, k3);
        tj_[t] = (short)j;
    }
    __syncthreads();

    // LN1
    {
        const int k = tid >> 4, c = tid & 15;
        float s = 0.f;
        for (int j = 0; j < 16; ++j) s += xs[k][c + 16 * j];
        for (int off = 8; off; off >>= 1) s += __shfl_down(s, off, 16);
        float mean = __shfl(s, 0, 16) * (1.f / 256.f);
        float vs = 0.f;
        for (int j = 0; j < 16; ++j) { float d = xs[k][c + 16 * j] - mean; vs += d * d; }
        for (int off = 8; off; off >>= 1) vs += __shfl_down(vs, off, 16);
        float rstd = rsqrtf(__shfl(vs, 0, 16) * (1.f / 256.f) + LN_EPS);
        for (int j = 0; j < 16; ++j) {
            int cc = c + 16 * j;
            xs[k][cc] = (xs[k][cc] - mean) * rstd * g1[cc] + b1[cc];
        }
    }
    __syncthreads();

    // store xn (bf16) for k1b
    for (int i = 0; i < 16; ++i) {
        int idx = tid + i * 256;
        xnbuf[(size_t)b * 4096 + idx] = f2bf(xs[idx >> 8][idx & 255]);
    }

    // P = xn @ Wg + bg
    {
        const int k = tid >> 4, c = tid & 15;
        float acc = bg[c];
        for (int q = 0; q < 256; ++q) acc += xs[k][q] * Wg[q * 16 + c];
        Pl[k][c] = acc;
    }
    __syncthreads();
    {
        const int k = tid >> 4, l = tid & 15;
        float d = 0.f;
        for (int c = 0; c < 16; ++c) d += Pl[k][c] * Pl[l][c];
        dotm[k][l] = d;
    }
    __syncthreads();
    {
        const int k = tid >> 4, l = tid & 15;
        float v = dotm[k][k] + dotm[l][l] - 2.f * dotm[k][l];
        Dsq[k][l] = fmaxf(v, 0.f) * mk[k] * mk[l];
    }

    for (int s = 0; s < 3; ++s) {
        __syncthreads();
        const float sig2 = expf(2.f * ls[s]);
        const float inv2 = 1.f / (2.f * sig2 + 1e-8f);
        if (tid < 120) {
            int u = eu_[tid], v = ev_[tid];
            W1s[tid] = expf(-Dsq[u][v] * inv2) * mk[u] * mk[v];
        }
        // A1 init = term_down closed form + tau*ABS (s-independent values)
        for (int idx = tid; idx < 1920; idx += 256) {
            int k = idx / 120, f = idx - k * 120;
            int u = eu_[f], v = ev_[f];
            float gu = (u == k) ? (float)(2 * k - 15) : ((u > k) ? 1.f : -1.f);
            float gv = (v == k) ? (float)(2 * k - 15) : ((v > k) ? 1.f : -1.f);
            float val = -gu * mk[u] + gv * mk[v];
            if (u == k || v == k) val += TAU;
            A1[k][f] = val;
        }
        __syncthreads();
        // triangle scatter: ABS@B2 column = 2*e_mid; signs (ij:+, ik:-, jk:+)
        for (int t = tid; t < 560; t += 256) {
            int e_ij = te1[t], e_ik = te2[t], e_jk = te3[t], jm = tj_[t];
            float t2 = 2.f * W1s[e_ij] * W1s[e_jk] * W1s[e_ik];
            atomicAdd(&A1[jm][e_ij], t2);
            atomicAdd(&A1[jm][e_ik], -t2);
            atomicAdd(&A1[jm][e_jk], t2);
        }
        __syncthreads();
        // Gm, L0 -> Mbuf; gg -> gbuf
        {
            const int k = tid >> 4, m = tid & 15;
            float gsum = 0.f;
            for (int o = 0; o < 16; ++o) {
                if (o == m) continue;
                int f = (o < m) ? eidx(o, m) : eidx(m, o);
                gsum += A1[k][f];
            }
            float l0;
            if (k == m) {
                float dsum = 0.f;
                for (int o = 0; o < 16; ++o)
                    if (o != k) dsum += W1s[(o < k) ? eidx(o, k) : eidx(k, o)];
                l0 = dsum + TAU;
            } else {
                l0 = -W1s[(k < m) ? eidx(k, m) : eidx(m, k)];
            }
            Mbuf[((size_t)b * 6 + s) * 256 + k * 16 + m] = l0;
            Mbuf[((size_t)b * 6 + 3 + s) * 256 + k * 16 + m] = gsum;
        }
        {
            const int k = tid >> 4, c = tid & 15;
            float p = 0.f;
            for (int f = c; f < 120; f += 16) p += A1[k][f];
            for (int off = 8; off; off >>= 1) p += __shfl_down(p, off, 16);
            if (c == 0) gbuf[(size_t)(b * 16 + k) * 3 + s] = p;
        }
    }
}

// ---------------------------------------------------------------------------
// K1b: Mcat[b*16+k][colbase+q] = sum_l M_rt[k][l] * xn[b][l][q]
// ---------------------------------------------------------------------------
__global__ __launch_bounds__(256) void k1b_mcat(const float* __restrict__ Mbuf,
                                                const ushort_t* __restrict__ xnbuf,
                                                ushort_t* __restrict__ Mcat) {
    const int b = blockIdx.x;
    const int tid = threadIdx.x;
    __shared__ float Ms[96][16];
    for (int i = 0; i < 6; ++i)
        ((float*)Ms)[tid + i * 256] = Mbuf[(size_t)b * 1536 + tid + i * 256];
    float xv[16];
#pragma unroll
    for (int l = 0; l < 16; ++l) xv[l] = bf2f(xnbuf[(size_t)b * 4096 + l * 256 + tid]);
    __syncthreads();
    const size_t obase = (size_t)b * 16 * 1536;
#pragma unroll
    for (int rt = 0; rt < 6; ++rt) {
        const int colbase = (rt < 3) ? rt * 256 : 768 + (rt - 3) * 256;
#pragma unroll
        for (int k = 0; k < 16; ++k) {
            const float4* mr = (const float4*)&Ms[rt * 16 + k][0];
            float4 m0 = mr[0], m1 = mr[1], m2 = mr[2], m3 = mr[3];
            float acc = m0.x * xv[0] + m0.y * xv[1] + m0.z * xv[2] + m0.w * xv[3]
                      + m1.x * xv[4] + m1.y * xv[5] + m1.z * xv[6] + m1.w * xv[7]
                      + m2.x * xv[8] + m2.y * xv[9] + m2.z * xv[10] + m2.w * xv[11]
                      + m3.x * xv[12] + m3.y * xv[13] + m3.z * xv[14] + m3.w * xv[15];
            Mcat[obase + (size_t)k * 1536 + colbase + tid] = f2bf(acc);
        }
    }
}

// ---------------------------------------------------------------------------
// MFMA GEMM core: BM=64, BN=128, BK=32, 4 waves (2x2), wave-tile 32x64.
// A: (M,K) bf16 row-major. Bt: (N,K) bf16 N-major. global_load_lds staging.
// ---------------------------------------------------------------------------
__device__ __forceinline__ void gemm_core(const ushort_t* __restrict__ A,
                                          const ushort_t* __restrict__ Bt,
                                          int Kdim, int m0, int n0,
                                          f32x4 acc[2][4],
                                          ushort_t (*As)[32], ushort_t (*Bs)[32]) {
    const int tid = threadIdx.x;
    const int wave = tid >> 6, lane = tid & 63;
    const int lq = lane >> 4, lr = lane & 15;
    const int wm = wave >> 1, wn = wave & 1;
    const int r = tid >> 2, ca = (tid & 3) << 3;
    const ushort_t* Ag = A + (size_t)(m0 + r) * Kdim + ca;
    const ushort_t* Bg0 = Bt + (size_t)(n0 + r) * Kdim + ca;
    const ushort_t* Bg1 = Bt + (size_t)(n0 + 64 + r) * Kdim + ca;
    char* AsD = (char*)As + wave * 1024;
    char* Bs0D = (char*)Bs + wave * 1024;
    char* Bs1D = (char*)Bs + 4096 + wave * 1024;
    for (int kt = 0; kt < Kdim; kt += 32) {
        __syncthreads();
        glds16(Ag + kt, AsD);
        glds16(Bg0 + kt, Bs0D);
        glds16(Bg1 + kt, Bs1D);
        __syncthreads();
        short8 af[2], bfr[4];
#pragma unroll
        for (int i = 0; i < 2; ++i) af[i] = *(const short8*)&As[wm * 32 + i * 16 + lr][lq * 8];
#pragma unroll
        for (int j = 0; j < 4; ++j) bfr[j] = *(const short8*)&Bs[wn * 64 + j * 16 + lr][lq * 8];
#pragma unroll
        for (int i = 0; i < 2; ++i)
#pragma unroll
            for (int j = 0; j < 4; ++j)
                acc[i][j] = __builtin_amdgcn_mfma_f32_16x16x32_bf16(af[i], bfr[j], acc[i][j], 0, 0, 0);
    }
}

// K2: Z = Mcat @ Wcat; epilogue x' = x + Z + cvec + sum_s g*beWo_s
__global__ __launch_bounds__(256) void k2_gemm(
    const ushort_t* __restrict__ Mcat, const ushort_t* __restrict__ WcatT,
    const float* __restrict__ xin, const float* __restrict__ cvec,
    const float* __restrict__ beWo, const float* __restrict__ gbuf,
    float* __restrict__ xp) {
    __shared__ ushort_t As[64][32];
    __shared__ ushort_t Bs[128][32];
    __shared__ float cvS[256], bewS[3][256], gblk[64][3];
    const int tid = threadIdx.x;
    const int bx = blockIdx.x;
    const int m0 = (bx >> 1) * 64;
    const int n0 = (bx & 1) * 128;
    cvS[tid] = cvec[tid];
    bewS[0][tid] = beWo[tid];
    bewS[1][tid] = beWo[256 + tid];
    bewS[2][tid] = beWo[512 + tid];
    if (tid < 192) { int rr = tid / 3, s = tid - rr * 3; gblk[rr][s] = gbuf[(size_t)(m0 + rr) * 3 + s]; }
    f32x4 acc[2][4] = {};
    gemm_core(Mcat, WcatT, 1536, m0, n0, acc, As, Bs);
    const int wave = tid >> 6, lane = tid & 63, lq = lane >> 4, lr = lane & 15;
    const int wm = wave >> 1, wn = wave & 1;
#pragma unroll
    for (int i = 0; i < 2; ++i)
#pragma unroll
        for (int j = 0; j < 4; ++j) {
            int n = n0 + wn * 64 + j * 16 + lr;
#pragma unroll
            for (int v = 0; v < 4; ++v) {
                int rl = wm * 32 + i * 16 + lq * 4 + v;
                size_t idx = (size_t)(m0 + rl) * 256 + n;
                float z = acc[i][j][v] + xin[idx] + cvS[n] + gblk[rl][0] * bewS[0][n] +
                          gblk[rl][1] * bewS[1][n] + gblk[rl][2] * bewS[2][n];
                xp[idx] = z;
            }
        }
}

// LN2 -> h (bf16)
__global__ __launch_bounds__(256) void k_ln2(const float* __restrict__ xp,
                                             const float* __restrict__ g2,
                                             const float* __restrict__ b2,
                                             ushort_t* __restrict__ h) {
    const int tid = threadIdx.x;
    const int row = blockIdx.x * 4 + (tid >> 6);
    const int lane = tid & 63;
    const float* xr = xp + (size_t)row * 256;
    float v0 = xr[lane], v1 = xr[lane + 64], v2 = xr[lane + 128], v3 = xr[lane + 192];
    float s = v0 + v1 + v2 + v3;
    for (int m = 32; m; m >>= 1) s += __shfl_xor(s, m, 64);
    float mean = s * (1.f / 256.f);
    float d0 = v0 - mean, d1 = v1 - mean, d2 = v2 - mean, d3 = v3 - mean;
    float q = d0 * d0 + d1 * d1 + d2 * d2 + d3 * d3;
    for (int m = 32; m; m >>= 1) q += __shfl_xor(q, m, 64);
    float rstd = rsqrtf(q * (1.f / 256.f) + LN_EPS);
    ushort_t* hr = h + (size_t)row * 256;
    hr[lane] = f2bf(d0 * rstd * g2[lane] + b2[lane]);
    hr[lane + 64] = f2bf(d1 * rstd * g2[lane + 64] + b2[lane + 64]);
    hr[lane + 128] = f2bf(d2 * rstd * g2[lane + 128] + b2[lane + 128]);
    hr[lane + 192] = f2bf(d3 * rstd * g2[lane + 192] + b2[lane + 192]);
}

// K3: F1g = gelu(h @ Wf1 + bf1) bf16
__global__ __launch_bounds__(256) void k3_gemm(const ushort_t* __restrict__ h,
                                               const ushort_t* __restrict__ Wf1T,
                                               const float* __restrict__ bf1,
                                               ushort_t* __restrict__ F1g) {
    __shared__ ushort_t As[64][32];
    __shared__ ushort_t Bs[128][32];
    const int tid = threadIdx.x;
    const int bx = blockIdx.x;
    const int m0 = (bx >> 3) * 64;
    const int n0 = (bx & 7) * 128;
    f32x4 acc[2][4] = {};
    gemm_core(h, Wf1T, 256, m0, n0, acc, As, Bs);
    const int wave = tid >> 6, lane = tid & 63, lq = lane >> 4, lr = lane & 15;
    const int wm = wave >> 1, wn = wave & 1;
#pragma unroll
    for (int i = 0; i < 2; ++i)
#pragma unroll
        for (int j = 0; j < 4; ++j) {
            int n = n0 + wn * 64 + j * 16 + lr;
#pragma unroll
            for (int v = 0; v < 4; ++v) {
                int rg = m0 + wm * 32 + i * 16 + lq * 4 + v;
                float u = acc[i][j][v] + bf1[n];
                float gl = 0.5f * u * (1.f + erff(u * 0.70710678118f));
                F1g[(size_t)rg * 1024 + n] = f2bf(gl);
            }
        }
}

// K4: out = x' + F1g @ Wf2 + bf2
__global__ __launch_bounds__(256) void k4_gemm(const ushort_t* __restrict__ F1g,
                                               const ushort_t* __restrict__ Wf2T,
                                               const float* __restrict__ bf2,
                                               const float* __restrict__ xp,
                                               float* __restrict__ out) {
    __shared__ ushort_t As[64][32];
    __shared__ ushort_t Bs[128][32];
    const int tid = threadIdx.x;
    const int bx = blockIdx.x;
    const int m0 = (bx >> 1) * 64;
    const int n0 = (bx & 1) * 128;
    f32x4 acc[2][4] = {};
    gemm_core(F1g, Wf2T, 1024, m0, n0, acc, As, Bs);
    const int wave = tid >> 6, lane = tid & 63, lq = lane >> 4, lr = lane & 15;
    const int wm = wave >> 1, wn = wave & 1;
#pragma unroll
    for (int i = 0; i < 2; ++i)
#pragma unroll
        for (int j = 0; j < 4; ++j) {
            int n = n0 + wn * 64 + j * 16 + lr;
#pragma unroll
            for (int v = 0; v < 4; ++v) {
                int rl = wm * 32 + i * 16 + lq * 4 + v;
                size_t idx = (size_t)(m0 + rl) * 256 + n;
                out[idx] = xp[idx] + acc[i][j][v] + bf2[n];
            }
        }
}

extern "C" void kernel_launch(void* const* d_in, const int* in_sizes, int n_in,
                              void* d_out, int out_size, void* d_ws, size_t ws_size,
                              hipStream_t stream) {
    const float* x = (const float*)d_in[0];
    const float* mask = (const float*)d_in[1];
    const float* Wg = (const float*)d_in[2];
    const float* bg = (const float*)d_in[3];
    const float* ls = (const float*)d_in[4];
    const float* Wv = (const float*)d_in[5];
    const float* bv = (const float*)d_in[6];
    const float* We = (const float*)d_in[7];
    const float* be = (const float*)d_in[8];
    const float* Wo = (const float*)d_in[9];
    const float* bo = (const float*)d_in[10];
    const float* g1 = (const float*)d_in[11];
    const float* b1 = (const float*)d_in[12];
    const float* g2 = (const float*)d_in[13];
    const float* b2 = (const float*)d_in[14];
    const float* Wf1 = (const float*)d_in[15];
    const float* bf1 = (const float*)d_in[16];
    const float* Wf2 = (const float*)d_in[17];
    const float* bf2 = (const float*)d_in[18];
    float* out = (float*)d_out;

    char* ws = (char*)d_ws;
    ushort_t* Mcat = (ushort_t*)(ws);                   // 50,331,648 B
    ushort_t* WcatT = (ushort_t*)(ws + 50331648);       //    786,432
    ushort_t* Wf1T = (ushort_t*)(ws + 51118080);        //    524,288
    ushort_t* Wf2T = (ushort_t*)(ws + 51642368);        //    524,288
    float* cvec = (float*)(ws + 52166656);              //      1,024
    float* beWo = (float*)(ws + 52167680);              //      3,072
    float* gbuf = (float*)(ws + 52170752);              //    196,608
    float* xp = (float*)(ws + 52367360);                // 16,777,216
    ushort_t* h = (ushort_t*)(ws + 69144576);           //  8,388,608
    ushort_t* F1g = (ushort_t*)(ws + 77533184);         // 33,554,432
    // xnbuf & Mbuf alias the F1g region (dead before k3 writes F1g)
    ushort_t* xnbuf = (ushort_t*)(ws + 77533184);       //  8,388,608
    float* Mbuf = (float*)(ws + 85921792);              //  6,291,456

    kw_wcat<<<dim3(1536), dim3(256), 0, stream>>>(Wv, We, Wo, WcatT);
    kw_vec<<<dim3(1), dim3(256), 0, stream>>>(bv, be, Wo, bo, cvec, beWo);
    kw_tr1<<<dim3(1024), dim3(256), 0, stream>>>(Wf1, Wf1T);
    kw_tr2<<<dim3(256), dim3(256), 0, stream>>>(Wf2, Wf2T);
    k1a_graph<<<dim3(1024), dim3(256), 0, stream>>>(x, mask, Wg, bg, ls, g1, b1, xnbuf, Mbuf, gbuf);
    k1b_mcat<<<dim3(1024), dim3(256), 0, stream>>>(Mbuf, xnbuf, Mcat);
    k2_gemm<<<dim3(512), dim3(256), 0, stream>>>(Mcat, WcatT, x, cvec, beWo, gbuf, xp);
    k_ln2<<<dim3(4096), dim3(256), 0, stream>>>(xp, g2, b2, h);
    k3_gemm<<<dim3(2048), dim3(256), 0, stream>>>(h, Wf1T, bf1, F1g);
    k4_gemm<<<dim3(512), dim3(256), 0, stream>>>(F1g, Wf2T, bf2, xp, out);
}

// Round 3
// 275.558 us; speedup vs baseline: 1.3434x; 1.1564x over previous
//
#include <hip/hip_runtime.h>
#include <hip/hip_bf16.h>
#include <cstdint>
#include <cstddef>

#define TAU 1e-4f
#define LN_EPS 1e-5f

typedef unsigned short ushort_t;
typedef unsigned int uint_t;
typedef __attribute__((ext_vector_type(8))) short short8;
typedef __attribute__((ext_vector_type(4))) float f32x4;

__device__ __forceinline__ ushort_t f2bf(float f) {
    union { float f; unsigned int u; } c; c.f = f;
    unsigned int r = (c.u + 0x7fffu + ((c.u >> 16) & 1u)) >> 16;
    return (ushort_t)r;
}
__device__ __forceinline__ float bf2f(ushort_t u) {
    union { unsigned int u; float f; } c; c.u = ((unsigned int)u) << 16;
    return c.f;
}
__device__ __forceinline__ int eidx(int i, int j) {
    return i * 15 - (i * (i - 1)) / 2 + (j - i - 1);
}
__device__ __forceinline__ void glds16(const void* g, void* l) {
    __builtin_amdgcn_global_load_lds((const __attribute__((address_space(1))) unsigned int*)g,
                                     (__attribute__((address_space(3))) unsigned int*)l,
                                     16, 0, 0);
}

// ---------------------------------------------------------------------------
// Prep: Wtmp[(rt*256+q)*256+n] = fused Wv/We @ Wo slice (fp32, coalesced)
// grid (64, 6): qg, w=(half*3+s)
// ---------------------------------------------------------------------------
__global__ __launch_bounds__(256) void kw_wcat(const float* __restrict__ Wv,
                                               const float* __restrict__ We,
                                               const float* __restrict__ Wo,
                                               float* __restrict__ Wtmp) {
    __shared__ float rowS[4][256];
    const int tid = threadIdx.x;
    const int q0 = blockIdx.x * 4;
    const int w = blockIdx.y;
    const int half = w / 3, s = w - half * 3;
    const float* src = half ? We : Wv;
#pragma unroll
    for (int r = 0; r < 4; ++r)
        rowS[r][tid] = src[(size_t)(q0 + r) * 768 + s * 256 + tid];
    __syncthreads();
    const float* wo = Wo + (size_t)(half * 768 + s * 256) * 256 + tid;
    float a0 = 0.f, a1 = 0.f, a2 = 0.f, a3 = 0.f;
    for (int d = 0; d < 256; ++d) {
        float wv = wo[(size_t)d * 256];
        a0 += rowS[0][d] * wv; a1 += rowS[1][d] * wv;
        a2 += rowS[2][d] * wv; a3 += rowS[3][d] * wv;
    }
    const int rt = half * 3 + s;
    Wtmp[(size_t)(rt * 256 + q0 + 0) * 256 + tid] = a0;
    Wtmp[(size_t)(rt * 256 + q0 + 1) * 256 + tid] = a1;
    Wtmp[(size_t)(rt * 256 + q0 + 2) * 256 + tid] = a2;
    Wtmp[(size_t)(rt * 256 + q0 + 3) * 256 + tid] = a3;
}

// transpose Wtmp per-rt block -> WkT[(rt*256+n)*256+q] bf16. grid (4,4,6)
__global__ __launch_bounds__(256) void kw_wkt(const float* __restrict__ Wtmp,
                                              ushort_t* __restrict__ WkT) {
    __shared__ float tS[64][65];
    const int tid = threadIdx.x;
    const int q0 = blockIdx.x * 64, n0 = blockIdx.y * 64, rt = blockIdx.z;
    const int rl = tid >> 6, cl = tid & 63;
#pragma unroll
    for (int p = 0; p < 16; ++p) {
        int r = p * 4 + rl;
        tS[r][cl] = Wtmp[(size_t)(rt * 256 + q0 + r) * 256 + n0 + cl];
    }
    __syncthreads();
#pragma unroll
    for (int p = 0; p < 16; ++p) {
        int r = p * 4 + rl;
        WkT[(size_t)(rt * 256 + n0 + r) * 256 + q0 + cl] = f2bf(tS[cl][r]);
    }
}

// grid 6: (half, s) -> cvpart[s][n] or beWo[s][n]
__global__ __launch_bounds__(256) void kw_vec(const float* __restrict__ bv,
                                              const float* __restrict__ be,
                                              const float* __restrict__ Wo,
                                              float* __restrict__ cvpart,
                                              float* __restrict__ beWo) {
    __shared__ float vS[256];
    const int tid = threadIdx.x;
    const int w = blockIdx.x;
    const int half = w / 3, s = w - half * 3;
    const float* vec = half ? be : bv;
    vS[tid] = vec[s * 256 + tid];
    __syncthreads();
    const float* wo = Wo + (size_t)(half * 768 + s * 256) * 256 + tid;
    float acc = 0.f;
    for (int d = 0; d < 256; ++d) acc += vS[d] * wo[(size_t)d * 256];
    if (half) beWo[s * 256 + tid] = acc;
    else cvpart[s * 256 + tid] = acc;
}

// Wf1 (256x1024) -> Wf1T[n*256+k] bf16. grid (4,16) tiles 64x64
__global__ __launch_bounds__(256) void kw_tr1(const float* __restrict__ Wf1,
                                              ushort_t* __restrict__ Wf1T) {
    __shared__ float tS[64][65];
    const int tid = threadIdx.x;
    const int k0 = blockIdx.x * 64, n0 = blockIdx.y * 64;
    const int rl = tid >> 6, cl = tid & 63;
#pragma unroll
    for (int p = 0; p < 16; ++p) {
        int r = p * 4 + rl;
        tS[r][cl] = Wf1[(size_t)(k0 + r) * 1024 + n0 + cl];
    }
    __syncthreads();
#pragma unroll
    for (int p = 0; p < 16; ++p) {
        int r = p * 4 + rl;
        Wf1T[(size_t)(n0 + r) * 256 + k0 + cl] = f2bf(tS[cl][r]);
    }
}

// Wf2 (1024x256) -> Wf2T[n*1024+k] bf16. grid (16,4)
__global__ __launch_bounds__(256) void kw_tr2(const float* __restrict__ Wf2,
                                              ushort_t* __restrict__ Wf2T) {
    __shared__ float tS[64][65];
    const int tid = threadIdx.x;
    const int k0 = blockIdx.x * 64, n0 = blockIdx.y * 64;
    const int rl = tid >> 6, cl = tid & 63;
#pragma unroll
    for (int p = 0; p < 16; ++p) {
        int r = p * 4 + rl;
        tS[r][cl] = Wf2[(size_t)(k0 + r) * 256 + n0 + cl];
    }
    __syncthreads();
#pragma unroll
    for (int p = 0; p < 16; ++p) {
        int r = p * 4 + rl;
        Wf2T[(size_t)(n0 + r) * 1024 + k0 + cl] = f2bf(tS[cl][r]);
    }
}

// ---------------------------------------------------------------------------
// K1a: per-b graph algebra, s-parallel. Outputs xn (bf16), Mbuf, gbuf.
// ---------------------------------------------------------------------------
__global__ __launch_bounds__(256) void k1a_graph(
    const float* __restrict__ xg, const float* __restrict__ maskg,
    const float* __restrict__ Wg, const float* __restrict__ bg,
    const float* __restrict__ ls, const float* __restrict__ g1,
    const float* __restrict__ b1, ushort_t* __restrict__ xnbuf,
    float* __restrict__ Mbuf, float* __restrict__ gbuf) {
    const int b = blockIdx.x;
    const int tid = threadIdx.x;
    // U union: phase1 {xs[16][257], Pl[16][17], dotm[16][17]} / phase2 A1[3][16][124]
    __shared__ __align__(16) float U[5952];
#define XS(k, c) U[(k) * 257 + (c)]
#define PL(k, c) U[4112 + (k) * 17 + (c)]
#define DMT(k, c) U[4384 + (k) * 17 + (c)]
#define A1E(s, k, f) U[(s) * 1984 + (k) * 124 + (f)]
    __shared__ float Dsq[16][17];
    __shared__ float W1all[3][120];
    __shared__ float mk[16];
    __shared__ short eu_[120], ev_[120];
    __shared__ short te1[560], te2[560], te3[560], tj_[560];

    const float* xb = xg + (size_t)b * 4096;
#pragma unroll
    for (int i = 0; i < 4; ++i) {
        int idx = tid * 4 + i * 1024;
        int k = idx >> 8, c = idx & 255;
        float4 v = *(const float4*)&xb[idx];
        XS(k, c) = v.x; XS(k, c + 1) = v.y; XS(k, c + 2) = v.z; XS(k, c + 3) = v.w;
    }
    if (tid < 16) mk[tid] = maskg[b * 16 + tid];
    if (tid < 120) {
        int rem = tid, i = 0;
        while (rem >= 15 - i) { rem -= 15 - i; ++i; }
        eu_[tid] = (short)i; ev_[tid] = (short)(i + 1 + rem);
    }
    for (int t = tid; t < 560; t += 256) {
        int rem = t, i = 0;
        while (rem >= ((15 - i) * (14 - i)) / 2) { rem -= ((15 - i) * (14 - i)) / 2; ++i; }
        int j = i + 1;
        while (rem >= 15 - j) { rem -= 15 - j; ++j; }
        int k3 = j + 1 + rem;
        te1[t] = (short)eidx(i, j);
        te2[t] = (short)eidx(i, k3);
        te3[t] = (short)eidx(j, k3);
        tj_[t] = (short)j;
    }
    __syncthreads();

    // LN1
    {
        const int k = tid >> 4, c = tid & 15;
        float s = 0.f;
        for (int j = 0; j < 16; ++j) s += XS(k, c + 16 * j);
        for (int off = 8; off; off >>= 1) s += __shfl_down(s, off, 16);
        float mean = __shfl(s, 0, 16) * (1.f / 256.f);
        float vs = 0.f;
        for (int j = 0; j < 16; ++j) { float d = XS(k, c + 16 * j) - mean; vs += d * d; }
        for (int off = 8; off; off >>= 1) vs += __shfl_down(vs, off, 16);
        float rstd = rsqrtf(__shfl(vs, 0, 16) * (1.f / 256.f) + LN_EPS);
        for (int j = 0; j < 16; ++j) {
            int cc = c + 16 * j;
            XS(k, cc) = (XS(k, cc) - mean) * rstd * g1[cc] + b1[cc];
        }
    }
    __syncthreads();

    // xn (bf16, packed pairs)
#pragma unroll
    for (int i = 0; i < 8; ++i) {
        int idx2 = tid * 2 + i * 512;
        int k = idx2 >> 8, c = idx2 & 255;
        uint_t v = (uint_t)f2bf(XS(k, c)) | ((uint_t)f2bf(XS(k, c + 1)) << 16);
        *(uint_t*)&xnbuf[(size_t)b * 4096 + idx2] = v;
    }

    // P = xn @ Wg + bg
    {
        const int k = tid >> 4, c = tid & 15;
        float acc = bg[c];
        for (int q = 0; q < 256; ++q) acc += XS(k, q) * Wg[q * 16 + c];
        PL(k, c) = acc;
    }
    __syncthreads();
    {
        const int k = tid >> 4, l = tid & 15;
        float d = 0.f;
        for (int c = 0; c < 16; ++c) d += PL(k, c) * PL(l, c);
        DMT(k, l) = d;
    }
    __syncthreads();
    {
        const int k = tid >> 4, l = tid & 15;
        float v = DMT(k, k) + DMT(l, l) - 2.f * DMT(k, l);
        Dsq[k][l] = fmaxf(v, 0.f) * mk[k] * mk[l];
    }
    __syncthreads();   // Dsq done; U free for A1

    // (a) W1 for all s + A1 init (term_down + tau, s-independent)
    for (int idx = tid; idx < 360; idx += 256) {
        int s = idx / 120, t = idx - s * 120;
        int u = eu_[t], v = ev_[t];
        float inv2 = 1.f / (2.f * expf(2.f * ls[s]) + 1e-8f);
        W1all[s][t] = expf(-Dsq[u][v] * inv2) * mk[u] * mk[v];
    }
    for (int idx = tid; idx < 1920; idx += 256) {
        int k = idx / 120, f = idx - k * 120;
        int u = eu_[f], v = ev_[f];
        float gu = (u == k) ? (float)(2 * k - 15) : ((u > k) ? 1.f : -1.f);
        float gv = (v == k) ? (float)(2 * k - 15) : ((v > k) ? 1.f : -1.f);
        float val = -gu * mk[u] + gv * mk[v];
        if (u == k || v == k) val += TAU;
        A1E(0, k, f) = val; A1E(1, k, f) = val; A1E(2, k, f) = val;
    }
    __syncthreads();

    // (b) triangle scatter, all s
    for (int t = tid; t < 1680; t += 256) {
        int s = t / 560, tt = t - s * 560;
        int e_ij = te1[tt], e_ik = te2[tt], e_jk = te3[tt], jm = tj_[tt];
        float t2 = 2.f * W1all[s][e_ij] * W1all[s][e_jk] * W1all[s][e_ik];
        atomicAdd(&A1E(s, jm, e_ij), t2);
        atomicAdd(&A1E(s, jm, e_ik), -t2);
        atomicAdd(&A1E(s, jm, e_jk), t2);
    }
    __syncthreads();

    // (c) Gm, L0 -> Mbuf; gg -> gbuf
    {
        const int k = tid >> 4, m = tid & 15;
        float gs0 = 0.f, gs1 = 0.f, gs2 = 0.f;
        for (int o = 0; o < 16; ++o) {
            if (o == m) continue;
            int f = (o < m) ? eidx(o, m) : eidx(m, o);
            gs0 += A1E(0, k, f); gs1 += A1E(1, k, f); gs2 += A1E(2, k, f);
        }
        float l0s[3];
        if (k == m) {
            float d0 = 0.f, d1 = 0.f, d2 = 0.f;
            for (int o = 0; o < 16; ++o) {
                if (o == k) continue;
                int f = (o < k) ? eidx(o, k) : eidx(k, o);
                d0 += W1all[0][f]; d1 += W1all[1][f]; d2 += W1all[2][f];
            }
            l0s[0] = d0 + TAU; l0s[1] = d1 + TAU; l0s[2] = d2 + TAU;
        } else {
            int f = (k < m) ? eidx(k, m) : eidx(m, k);
            l0s[0] = -W1all[0][f]; l0s[1] = -W1all[1][f]; l0s[2] = -W1all[2][f];
        }
        float* mb = Mbuf + (size_t)b * 1536 + tid;
        mb[0] = l0s[0]; mb[256] = l0s[1]; mb[512] = l0s[2];
        mb[768] = gs0; mb[1024] = gs1; mb[1280] = gs2;
    }
    if (tid < 48) {
        const int kk = tid & 15, ss = tid >> 4;
        const float4* ap = (const float4*)&A1E(ss, kk, 0);
        float p = 0.f;
#pragma unroll
        for (int f4 = 0; f4 < 30; ++f4) {
            float4 v = ap[f4];
            p += v.x + v.y + v.z + v.w;
        }
        gbuf[b * 48 + kk * 3 + ss] = p;
    }
#undef XS
#undef PL
#undef DMT
#undef A1E
}

// ---------------------------------------------------------------------------
// gemm cores
// ---------------------------------------------------------------------------
__device__ __forceinline__ void gemm128(const ushort_t* __restrict__ A,
                                        const ushort_t* __restrict__ Bt,
                                        int Kdim, int m0, int n0,
                                        f32x4 acc[4][4],
                                        ushort_t (*As)[32], ushort_t (*Bs)[32]) {
    const int tid = threadIdx.x;
    const int wave = tid >> 6, lane = tid & 63;
    const int lq = lane >> 4, lr = lane & 15;
    const int wm = wave >> 1, wn = wave & 1;
    const int r = tid >> 2, ca = (tid & 3) << 3;
    const ushort_t* Ag0 = A + (size_t)(m0 + r) * Kdim + ca;
    const ushort_t* Ag1 = A + (size_t)(m0 + 64 + r) * Kdim + ca;
    const ushort_t* Bg0 = Bt + (size_t)(n0 + r) * Kdim + ca;
    const ushort_t* Bg1 = Bt + (size_t)(n0 + 64 + r) * Kdim + ca;
    char* AsD0 = (char*)As + wave * 1024;
    char* AsD1 = (char*)As + 4096 + wave * 1024;
    char* BsD0 = (char*)Bs + wave * 1024;
    char* BsD1 = (char*)Bs + 4096 + wave * 1024;
    for (int kt = 0; kt < Kdim; kt += 32) {
        __syncthreads();
        glds16(Ag0 + kt, AsD0);
        glds16(Ag1 + kt, AsD1);
        glds16(Bg0 + kt, BsD0);
        glds16(Bg1 + kt, BsD1);
        __syncthreads();
        short8 af[4], bfr[4];
#pragma unroll
        for (int i = 0; i < 4; ++i) af[i] = *(const short8*)&As[wm * 64 + i * 16 + lr][lq * 8];
#pragma unroll
        for (int j = 0; j < 4; ++j) bfr[j] = *(const short8*)&Bs[wn * 64 + j * 16 + lr][lq * 8];
#pragma unroll
        for (int i = 0; i < 4; ++i)
#pragma unroll
            for (int j = 0; j < 4; ++j)
                acc[i][j] = __builtin_amdgcn_mfma_f32_16x16x32_bf16(af[i], bfr[j], acc[i][j], 0, 0, 0);
    }
}

__device__ __forceinline__ void gemm64(const ushort_t* __restrict__ A,
                                       const ushort_t* __restrict__ Bt,
                                       int Kdim, int m0, int n0,
                                       f32x4 acc[2][4],
                                       ushort_t (*As)[32], ushort_t (*Bs)[32]) {
    const int tid = threadIdx.x;
    const int wave = tid >> 6, lane = tid & 63;
    const int lq = lane >> 4, lr = lane & 15;
    const int wm = wave >> 1, wn = wave & 1;
    const int r = tid >> 2, ca = (tid & 3) << 3;
    const ushort_t* Ag = A + (size_t)(m0 + r) * Kdim + ca;
    const ushort_t* Bg0 = Bt + (size_t)(n0 + r) * Kdim + ca;
    const ushort_t* Bg1 = Bt + (size_t)(n0 + 64 + r) * Kdim + ca;
    char* AsD = (char*)As + wave * 1024;
    char* Bs0D = (char*)Bs + wave * 1024;
    char* Bs1D = (char*)Bs + 4096 + wave * 1024;
    for (int kt = 0; kt < Kdim; kt += 32) {
        __syncthreads();
        glds16(Ag + kt, AsD);
        glds16(Bg0 + kt, Bs0D);
        glds16(Bg1 + kt, Bs1D);
        __syncthreads();
        short8 af[2], bfr[4];
#pragma unroll
        for (int i = 0; i < 2; ++i) af[i] = *(const short8*)&As[wm * 32 + i * 16 + lr][lq * 8];
#pragma unroll
        for (int j = 0; j < 4; ++j) bfr[j] = *(const short8*)&Bs[wn * 64 + j * 16 + lr][lq * 8];
#pragma unroll
        for (int i = 0; i < 2; ++i)
#pragma unroll
            for (int j = 0; j < 4; ++j)
                acc[i][j] = __builtin_amdgcn_mfma_f32_16x16x32_bf16(af[i], bfr[j], acc[i][j], 0, 0, 0);
    }
}

// kY: Y = xn @ Wk' (M=16384, N=1536, K=256), 128x128 tiles, grid (128,12)
__global__ __launch_bounds__(256) void kY_gemm(const ushort_t* __restrict__ xn,
                                               const ushort_t* __restrict__ WkT,
                                               ushort_t* __restrict__ Y) {
    __shared__ ushort_t As[128][32];
    __shared__ ushort_t Bs[128][32];
    const int tid = threadIdx.x;
    const int m0 = blockIdx.x * 128, n0 = blockIdx.y * 128;
    f32x4 acc[4][4] = {};
    gemm128(xn, WkT, 256, m0, n0, acc, As, Bs);
    const int wave = tid >> 6, lane = tid & 63, lq = lane >> 4, lr = lane & 15;
    const int wm = wave >> 1, wn = wave & 1;
#pragma unroll
    for (int i = 0; i < 4; ++i)
#pragma unroll
        for (int j = 0; j < 4; ++j) {
            int n = n0 + wn * 64 + j * 16 + lr;
#pragma unroll
            for (int v = 0; v < 4; ++v) {
                int rg = m0 + wm * 64 + i * 16 + lq * 4 + v;
                Y[(size_t)rg * 1536 + n] = f2bf(acc[i][j][v]);
            }
        }
}

// kZ: per-b Z = sum_rt M_rt @ Y_rt; epilogue x'=x+Z+cv+sum g*beWo; fused LN2->h
__global__ __launch_bounds__(256) void kZ_apply(
    const ushort_t* __restrict__ Y, const float* __restrict__ Mbuf,
    const float* __restrict__ xin, const float* __restrict__ bo,
    const float* __restrict__ cvpart, const float* __restrict__ beWo,
    const float* __restrict__ gbuf, const float* __restrict__ g2,
    const float* __restrict__ b2, float* __restrict__ xp,
    ushort_t* __restrict__ h) {
    __shared__ __align__(16) char YsRaw[49152];
    ushort_t* Ys = (ushort_t*)YsRaw;
    float (*xpS)[260] = (float(*)[260])YsRaw;
    __shared__ float Ms[1536];
    __shared__ float gS[48];
    __shared__ float mrS[16][2];
    const int b = blockIdx.x, tid = threadIdx.x;
    const int wave = tid >> 6, lane = tid & 63;
    const char* Ybc = (const char*)(Y + (size_t)b * 24576);
#pragma unroll
    for (int it = 0; it < 12; ++it) {
        int base = it * 4096 + wave * 1024;
        glds16(Ybc + base + lane * 16, YsRaw + base);
    }
#pragma unroll
    for (int i = 0; i < 6; ++i) Ms[tid + i * 256] = Mbuf[(size_t)b * 1536 + tid + i * 256];
    if (tid < 48) gS[tid] = gbuf[b * 48 + tid];
    __syncthreads();

    const int q = tid;
    float yv[96];
#pragma unroll
    for (int rt = 0; rt < 6; ++rt)
#pragma unroll
        for (int l = 0; l < 16; ++l)
            yv[rt * 16 + l] = bf2f(Ys[l * 1536 + rt * 256 + q]);

    float accv[16];
#pragma unroll
    for (int k = 0; k < 16; ++k) {
        float a = 0.f;
#pragma unroll
        for (int rt = 0; rt < 6; ++rt) {
            const float4* mp = (const float4*)&Ms[rt * 256 + k * 16];
            float4 m0 = mp[0], m1 = mp[1], m2 = mp[2], m3 = mp[3];
            const float* yp = &yv[rt * 16];
            a += m0.x * yp[0] + m0.y * yp[1] + m0.z * yp[2] + m0.w * yp[3]
               + m1.x * yp[4] + m1.y * yp[5] + m1.z * yp[6] + m1.w * yp[7]
               + m2.x * yp[8] + m2.y * yp[9] + m2.z * yp[10] + m2.w * yp[11]
               + m3.x * yp[12] + m3.y * yp[13] + m3.z * yp[14] + m3.w * yp[15];
        }
        accv[k] = a;
    }

    float cv = bo[q] + TAU * (cvpart[q] + cvpart[256 + q] + cvpart[512 + q]);
    float bw0 = beWo[q], bw1 = beWo[256 + q], bw2 = beWo[512 + q];
    const float* xb2 = xin + (size_t)b * 4096;
    float* xpb = xp + (size_t)b * 4096;
    float xpv[16];
#pragma unroll
    for (int k = 0; k < 16; ++k) {
        xpv[k] = accv[k] + xb2[k * 256 + q] + cv +
                 gS[k * 3] * bw0 + gS[k * 3 + 1] * bw1 + gS[k * 3 + 2] * bw2;
        xpb[k * 256 + q] = xpv[k];
    }
    __syncthreads();   // all Ys reads done
#pragma unroll
    for (int k = 0; k < 16; ++k) xpS[k][q] = xpv[k];
    __syncthreads();

    {
        const int kk = tid >> 4, c = tid & 15;
        float s = 0.f;
        for (int j = 0; j < 16; ++j) s += xpS[kk][c + 16 * j];
        for (int off = 8; off; off >>= 1) s += __shfl_down(s, off, 16);
        float mean = __shfl(s, 0, 16) * (1.f / 256.f);
        float vs = 0.f;
        for (int j = 0; j < 16; ++j) { float d = xpS[kk][c + 16 * j] - mean; vs += d * d; }
        for (int off = 8; off; off >>= 1) vs += __shfl_down(vs, off, 16);
        float rstd = rsqrtf(__shfl(vs, 0, 16) * (1.f / 256.f) + LN_EPS);
        if (c == 0) { mrS[kk][0] = mean; mrS[kk][1] = rstd; }
    }
    __syncthreads();
    ushort_t* hb = h + (size_t)b * 4096;
    const float g2q = g2[q], b2q = b2[q];
#pragma unroll
    for (int k = 0; k < 16; ++k) {
        float m = mrS[k][0], r = mrS[k][1];
        hb[k * 256 + q] = f2bf((xpS[k][q] - m) * r * g2q + b2q);
    }
}

// K3: F1g = gelu(h @ Wf1 + bf1), 128x128, grid (128,8)
__global__ __launch_bounds__(256) void k3_gemm(const ushort_t* __restrict__ h,
                                               const ushort_t* __restrict__ Wf1T,
                                               const float* __restrict__ bf1,
                                               ushort_t* __restrict__ F1g) {
    __shared__ ushort_t As[128][32];
    __shared__ ushort_t Bs[128][32];
    const int tid = threadIdx.x;
    const int m0 = blockIdx.x * 128, n0 = blockIdx.y * 128;
    f32x4 acc[4][4] = {};
    gemm128(h, Wf1T, 256, m0, n0, acc, As, Bs);
    const int wave = tid >> 6, lane = tid & 63, lq = lane >> 4, lr = lane & 15;
    const int wm = wave >> 1, wn = wave & 1;
#pragma unroll
    for (int i = 0; i < 4; ++i)
#pragma unroll
        for (int j = 0; j < 4; ++j) {
            int n = n0 + wn * 64 + j * 16 + lr;
            float bn = bf1[n];
#pragma unroll
            for (int v = 0; v < 4; ++v) {
                int rg = m0 + wm * 64 + i * 16 + lq * 4 + v;
                float u = acc[i][j][v] + bn;
                float gl = 0.5f * u * (1.f + erff(u * 0.70710678118f));
                F1g[(size_t)rg * 1024 + n] = f2bf(gl);
            }
        }
}

// K4: out = xp + F1g @ Wf2 + bf2, 64x128, grid (256,2)
__global__ __launch_bounds__(256) void k4_gemm(const ushort_t* __restrict__ F1g,
                                               const ushort_t* __restrict__ Wf2T,
                                               const float* __restrict__ bf2,
                                               const float* __restrict__ xp,
                                               float* __restrict__ out) {
    __shared__ ushort_t As[64][32];
    __shared__ ushort_t Bs[128][32];
    const int tid = threadIdx.x;
    const int m0 = blockIdx.x * 64, n0 = blockIdx.y * 128;
    f32x4 acc[2][4] = {};
    gemm64(F1g, Wf2T, 1024, m0, n0, acc, As, Bs);
    const int wave = tid >> 6, lane = tid & 63, lq = lane >> 4, lr = lane & 15;
    const int wm = wave >> 1, wn = wave & 1;
#pragma unroll
    for (int i = 0; i < 2; ++i)
#pragma unroll
        for (int j = 0; j < 4; ++j) {
            int n = n0 + wn * 64 + j * 16 + lr;
            float bn = bf2[n];
#pragma unroll
            for (int v = 0; v < 4; ++v) {
                size_t idx = (size_t)(m0 + wm * 32 + i * 16 + lq * 4 + v) * 256 + n;
                out[idx] = xp[idx] + acc[i][j][v] + bn;
            }
        }
}

extern "C" void kernel_launch(void* const* d_in, const int* in_sizes, int n_in,
                              void* d_out, int out_size, void* d_ws, size_t ws_size,
                              hipStream_t stream) {
    const float* x = (const float*)d_in[0];
    const float* mask = (const float*)d_in[1];
    const float* Wg = (const float*)d_in[2];
    const float* bg = (const float*)d_in[3];
    const float* ls = (const float*)d_in[4];
    const float* Wv = (const float*)d_in[5];
    const float* bv = (const float*)d_in[6];
    const float* We = (const float*)d_in[7];
    const float* be = (const float*)d_in[8];
    const float* Wo = (const float*)d_in[9];
    const float* bo = (const float*)d_in[10];
    const float* g1 = (const float*)d_in[11];
    const float* b1 = (const float*)d_in[12];
    const float* g2 = (const float*)d_in[13];
    const float* b2 = (const float*)d_in[14];
    const float* Wf1 = (const float*)d_in[15];
    const float* bf1 = (const float*)d_in[16];
    const float* Wf2 = (const float*)d_in[17];
    const float* bf2 = (const float*)d_in[18];
    float* out = (float*)d_out;

    char* ws = (char*)d_ws;
    ushort_t* Y = (ushort_t*)(ws);                      // 50,331,648
    ushort_t* F1g = (ushort_t*)(ws);                    // 33,554,432 (alias: Y dead after kZ)
    ushort_t* WkT = (ushort_t*)(ws + 50331648);         //    786,432
    ushort_t* Wf1T = (ushort_t*)(ws + 51118080);        //    524,288
    ushort_t* Wf2T = (ushort_t*)(ws + 51642368);        //    524,288
    float* cvpart = (float*)(ws + 52166656);            //      3,072
    float* beWo = (float*)(ws + 52169728);              //      3,072
    float* gbuf = (float*)(ws + 52172800);              //    196,608
    float* xp = (float*)(ws + 52369408);                // 16,777,216
    ushort_t* h = (ushort_t*)(ws + 69146624);           //  8,388,608
    ushort_t* xnbuf = (ushort_t*)(ws + 77535232);       //  8,388,608
    float* Wtmp = (float*)(ws + 77535232);              //  1,572,864 (alias: dead before k1a)
    float* Mbuf = (float*)(ws + 85923840);              //  6,291,456  -> end 92,215,296

    kw_wcat<<<dim3(64, 6), dim3(256), 0, stream>>>(Wv, We, Wo, Wtmp);
    kw_wkt<<<dim3(4, 4, 6), dim3(256), 0, stream>>>(Wtmp, WkT);
    kw_vec<<<dim3(6), dim3(256), 0, stream>>>(bv, be, Wo, cvpart, beWo);
    kw_tr1<<<dim3(4, 16), dim3(256), 0, stream>>>(Wf1, Wf1T);
    kw_tr2<<<dim3(16, 4), dim3(256), 0, stream>>>(Wf2, Wf2T);
    k1a_graph<<<dim3(1024), dim3(256), 0, stream>>>(x, mask, Wg, bg, ls, g1, b1, xnbuf, Mbuf, gbuf);
    kY_gemm<<<dim3(128, 12), dim3(256), 0, stream>>>(xnbuf, WkT, Y);
    kZ_apply<<<dim3(1024), dim3(256), 0, stream>>>(Y, Mbuf, x, bo, cvpart, beWo, gbuf, g2, b2, xp, h);
    k3_gemm<<<dim3(128, 8), dim3(256), 0, stream>>>(h, Wf1T, bf1, F1g);
    k4_gemm<<<dim3(256, 2), dim3(256), 0, stream>>>(F1g, Wf2T, bf2, xp, out);
}

// Round 4
// 270.070 us; speedup vs baseline: 1.3707x; 1.0203x over previous
//
#include <hip/hip_runtime.h>
#include <hip/hip_bf16.h>
#include <cstdint>
#include <cstddef>

#define TAU 1e-4f
#define LN_EPS 1e-5f

typedef unsigned short ushort_t;
typedef unsigned int uint_t;
typedef __attribute__((ext_vector_type(8))) short short8;
typedef __attribute__((ext_vector_type(4))) float f32x4;

__device__ __forceinline__ ushort_t f2bf(float f) {
    union { float f; unsigned int u; } c; c.f = f;
    unsigned int r = (c.u + 0x7fffu + ((c.u >> 16) & 1u)) >> 16;
    return (ushort_t)r;
}
__device__ __forceinline__ float bf2f(ushort_t u) {
    union { unsigned int u; float f; } c; c.u = ((unsigned int)u) << 16;
    return c.f;
}
__device__ __forceinline__ int eidx(int i, int j) {
    return i * 15 - (i * (i - 1)) / 2 + (j - i - 1);
}
__device__ __forceinline__ void glds16(const void* g, void* l) {
    __builtin_amdgcn_global_load_lds((const __attribute__((address_space(1))) unsigned int*)g,
                                     (__attribute__((address_space(3))) unsigned int*)l,
                                     16, 0, 0);
}

// ---------------------------------------------------------------------------
// Prep A: Wtmp[(rt*256+q)*256+n] = fused Wv/We @ Wo slice (fp32), plus the
// bias vectors (cvpart/beWo) on the bx==64 lane of the grid. grid (65,6).
// ---------------------------------------------------------------------------
__global__ __launch_bounds__(256) void kw_fuse(const float* __restrict__ Wv,
                                               const float* __restrict__ We,
                                               const float* __restrict__ Wo,
                                               const float* __restrict__ bv,
                                               const float* __restrict__ be,
                                               float* __restrict__ Wtmp,
                                               float* __restrict__ cvpart,
                                               float* __restrict__ beWo) {
    __shared__ float rowS[4][256];
    const int tid = threadIdx.x;
    const int w = blockIdx.y;
    const int half = w / 3, s = w - half * 3;
    if (blockIdx.x == 64) {
        // bias path
        const float* vec = half ? be : bv;
        rowS[0][tid] = vec[s * 256 + tid];
        __syncthreads();
        const float* wo = Wo + (size_t)(half * 768 + s * 256) * 256 + tid;
        float acc = 0.f;
        for (int d = 0; d < 256; ++d) acc += rowS[0][d] * wo[(size_t)d * 256];
        if (half) beWo[s * 256 + tid] = acc;
        else cvpart[s * 256 + tid] = acc;
        return;
    }
    const int q0 = blockIdx.x * 4;
    const float* src = half ? We : Wv;
#pragma unroll
    for (int r = 0; r < 4; ++r)
        rowS[r][tid] = src[(size_t)(q0 + r) * 768 + s * 256 + tid];
    __syncthreads();
    const float* wo = Wo + (size_t)(half * 768 + s * 256) * 256 + tid;
    float a0 = 0.f, a1 = 0.f, a2 = 0.f, a3 = 0.f;
    for (int d = 0; d < 256; ++d) {
        float wv = wo[(size_t)d * 256];
        a0 += rowS[0][d] * wv; a1 += rowS[1][d] * wv;
        a2 += rowS[2][d] * wv; a3 += rowS[3][d] * wv;
    }
    const int rt = half * 3 + s;
    Wtmp[(size_t)(rt * 256 + q0 + 0) * 256 + tid] = a0;
    Wtmp[(size_t)(rt * 256 + q0 + 1) * 256 + tid] = a1;
    Wtmp[(size_t)(rt * 256 + q0 + 2) * 256 + tid] = a2;
    Wtmp[(size_t)(rt * 256 + q0 + 3) * 256 + tid] = a3;
}

// ---------------------------------------------------------------------------
// Prep B: all fp32 -> bf16 transposes in one kernel. grid 224.
//   id<96:   Wtmp -> WkT  (per-rt 256x256 transpose)
//   id<160:  Wf1 (256x1024) -> Wf1T (1024x256)
//   else:    Wf2 (1024x256) -> Wf2T (256x1024)
// ---------------------------------------------------------------------------
__global__ __launch_bounds__(256) void kw_trans(const float* __restrict__ Wtmp,
                                                const float* __restrict__ Wf1,
                                                const float* __restrict__ Wf2,
                                                ushort_t* __restrict__ WkT,
                                                ushort_t* __restrict__ Wf1T,
                                                ushort_t* __restrict__ Wf2T) {
    __shared__ float tS[64][65];
    const int tid = threadIdx.x;
    const int id = blockIdx.x;
    const float* src; ushort_t* dst;
    int sr0, sc0, ss, dr0, dc0, ds_;
    if (id < 96) {
        int rt = id >> 4, rem = id & 15, qi = rem & 3, ni = rem >> 2;
        src = Wtmp; ss = 256; sr0 = rt * 256 + qi * 64; sc0 = ni * 64;
        dst = WkT; ds_ = 256; dr0 = rt * 256 + ni * 64; dc0 = qi * 64;
    } else if (id < 160) {
        int t = id - 96; int ki = t & 3, ni = t >> 2;
        src = Wf1; ss = 1024; sr0 = ki * 64; sc0 = ni * 64;
        dst = Wf1T; ds_ = 256; dr0 = ni * 64; dc0 = ki * 64;
    } else {
        int t = id - 160; int ki = t >> 2, ni = t & 3;
        src = Wf2; ss = 256; sr0 = ki * 64; sc0 = ni * 64;
        dst = Wf2T; ds_ = 1024; dr0 = ni * 64; dc0 = ki * 64;
    }
    const int rl = tid >> 6, cl = tid & 63;
#pragma unroll
    for (int p = 0; p < 16; ++p) {
        int r = p * 4 + rl;
        tS[r][cl] = src[(size_t)(sr0 + r) * ss + sc0 + cl];
    }
    __syncthreads();
#pragma unroll
    for (int p = 0; p < 16; ++p) {
        int r = p * 4 + rl;
        dst[(size_t)(dr0 + r) * ds_ + dc0 + cl] = f2bf(tS[cl][r]);
    }
}

// ---------------------------------------------------------------------------
// kLN1P: per-b LN1 -> xnbuf (bf16), P = xn@Wg+bg (fp32), Dsq -> Dsqbuf.
// ---------------------------------------------------------------------------
__global__ __launch_bounds__(256) void kLN1P(
    const float* __restrict__ xg, const float* __restrict__ maskg,
    const float* __restrict__ Wg, const float* __restrict__ bg,
    const float* __restrict__ g1, const float* __restrict__ b1,
    ushort_t* __restrict__ xnbuf, float* __restrict__ Dsqbuf) {
    __shared__ float XS[16][260];
    __shared__ float WgT[16][260];
    __shared__ float Pl[16][17];
    __shared__ float dotm[16][17];
    __shared__ float mk[16];
    const int b = blockIdx.x;
    const int tid = threadIdx.x;

    const float* xb = xg + (size_t)b * 4096;
#pragma unroll
    for (int i = 0; i < 4; ++i) {
        int idx = tid * 4 + i * 1024;
        int k = idx >> 8, c = idx & 255;
        float4 v = *(const float4*)&xb[idx];
        XS[k][c] = v.x; XS[k][c + 1] = v.y; XS[k][c + 2] = v.z; XS[k][c + 3] = v.w;
    }
    {
        const float4* wgp = (const float4*)(Wg + tid * 16);
        float4 w0 = wgp[0], w1 = wgp[1], w2 = wgp[2], w3 = wgp[3];
        WgT[0][tid] = w0.x; WgT[1][tid] = w0.y; WgT[2][tid] = w0.z; WgT[3][tid] = w0.w;
        WgT[4][tid] = w1.x; WgT[5][tid] = w1.y; WgT[6][tid] = w1.z; WgT[7][tid] = w1.w;
        WgT[8][tid] = w2.x; WgT[9][tid] = w2.y; WgT[10][tid] = w2.z; WgT[11][tid] = w2.w;
        WgT[12][tid] = w3.x; WgT[13][tid] = w3.y; WgT[14][tid] = w3.z; WgT[15][tid] = w3.w;
    }
    if (tid < 16) mk[tid] = maskg[b * 16 + tid];
    __syncthreads();

    // LN1
    {
        const int k = tid >> 4, c = tid & 15;
        float s = 0.f;
#pragma unroll
        for (int j = 0; j < 16; ++j) s += XS[k][c + 16 * j];
        for (int off = 8; off; off >>= 1) s += __shfl_down(s, off, 16);
        float mean = __shfl(s, 0, 16) * (1.f / 256.f);
        float vs = 0.f;
#pragma unroll
        for (int j = 0; j < 16; ++j) { float d = XS[k][c + 16 * j] - mean; vs += d * d; }
        for (int off = 8; off; off >>= 1) vs += __shfl_down(vs, off, 16);
        float rstd = rsqrtf(__shfl(vs, 0, 16) * (1.f / 256.f) + LN_EPS);
#pragma unroll
        for (int j = 0; j < 16; ++j) {
            int cc = c + 16 * j;
            XS[k][cc] = (XS[k][cc] - mean) * rstd * g1[cc] + b1[cc];
        }
    }
    __syncthreads();

    // xn (bf16, packed pairs)
#pragma unroll
    for (int i = 0; i < 8; ++i) {
        int idx2 = tid * 2 + i * 512;
        int k = idx2 >> 8, c = idx2 & 255;
        uint_t v = (uint_t)f2bf(XS[k][c]) | ((uint_t)f2bf(XS[k][c + 1]) << 16);
        *(uint_t*)&xnbuf[(size_t)b * 4096 + idx2] = v;
    }

    // P[k][c] = bg[c] + sum_q XS[k][q] * WgT[c][q]  (float4, fully unrolled)
    {
        const int k = tid >> 4, c = tid & 15;
        float acc = bg[c];
#pragma unroll
        for (int q4 = 0; q4 < 64; ++q4) {
            float4 wv = *(const float4*)&WgT[c][q4 * 4];
            float4 xv = *(const float4*)&XS[k][q4 * 4];
            acc += wv.x * xv.x + wv.y * xv.y + wv.z * xv.z + wv.w * xv.w;
        }
        Pl[k][c] = acc;
    }
    __syncthreads();
    {
        const int k = tid >> 4, l = tid & 15;
        float d = 0.f;
#pragma unroll
        for (int c = 0; c < 16; ++c) d += Pl[k][c] * Pl[l][c];
        dotm[k][l] = d;
    }
    __syncthreads();
    {
        const int k = tid >> 4, l = tid & 15;
        float v = dotm[k][k] + dotm[l][l] - 2.f * dotm[k][l];
        Dsqbuf[(size_t)b * 256 + tid] = fmaxf(v, 0.f) * mk[k] * mk[l];
    }
}

// ---------------------------------------------------------------------------
// k1c: graph algebra, one WAVE per (b,s). grid 768 x 256 (4 waves/block).
// ---------------------------------------------------------------------------
__global__ __launch_bounds__(256) void k1c_graph(
    const float* __restrict__ Dsqbuf, const float* __restrict__ maskg,
    const float* __restrict__ ls, float* __restrict__ Mbuf,
    float* __restrict__ gbuf) {
    __shared__ short eu_[120], ev_[120];
    __shared__ short te1[560], te2[560], te3[560], tj_[560];
    __shared__ short fmat[16][16];
    __shared__ float W1[4][128];
    __shared__ float A1[4][16][124];
    __shared__ float DsqW[4][256];
    __shared__ float mkW[4][16];
    const int tid = threadIdx.x;
    const int wave = tid >> 6, lane = tid & 63;
    const int pair = blockIdx.x * 4 + wave;
    const int b = pair / 3, s = pair - b * 3;

    if (tid < 120) {
        int rem = tid, i = 0;
        while (rem >= 15 - i) { rem -= 15 - i; ++i; }
        eu_[tid] = (short)i; ev_[tid] = (short)(i + 1 + rem);
    }
    if (tid < 256) {
        int a = tid >> 4, c = tid & 15;
        fmat[a][c] = (a == c) ? (short)0 : (short)((a < c) ? eidx(a, c) : eidx(c, a));
    }
    for (int t = tid; t < 560; t += 256) {
        int rem = t, i = 0;
        while (rem >= ((15 - i) * (14 - i)) / 2) { rem -= ((15 - i) * (14 - i)) / 2; ++i; }
        int j = i + 1;
        while (rem >= 15 - j) { rem -= 15 - j; ++j; }
        int k3 = j + 1 + rem;
        te1[t] = (short)eidx(i, j);
        te2[t] = (short)eidx(i, k3);
        te3[t] = (short)eidx(j, k3);
        tj_[t] = (short)j;
    }
    // stage per-wave Dsq + mask
#pragma unroll
    for (int i = 0; i < 4; ++i)
        DsqW[wave][lane + 64 * i] = Dsqbuf[(size_t)b * 256 + lane + 64 * i];
    if (lane < 16) mkW[wave][lane] = maskg[b * 16 + lane];
    __syncthreads();

    const float inv2 = 1.f / (2.f * expf(2.f * ls[s]) + 1e-8f);
    // W1 + A1 init (term_down closed form + tau)
#pragma unroll
    for (int hh = 0; hh < 2; ++hh) {
        int f = lane + 64 * hh;
        if (f < 120) {
            int u = eu_[f], v = ev_[f];
            W1[wave][f] = expf(-DsqW[wave][u * 16 + v] * inv2) * mkW[wave][u] * mkW[wave][v];
        }
    }
#pragma unroll
    for (int k = 0; k < 16; ++k) {
#pragma unroll
        for (int hh = 0; hh < 2; ++hh) {
            int f = lane + 64 * hh;
            if (f < 120) {
                int u = eu_[f], v = ev_[f];
                float gu = (u == k) ? (float)(2 * k - 15) : ((u > k) ? 1.f : -1.f);
                float gv = (v == k) ? (float)(2 * k - 15) : ((v > k) ? 1.f : -1.f);
                float val = -gu * mkW[wave][u] + gv * mkW[wave][v];
                if (u == k || v == k) val += TAU;
                A1[wave][k][f] = val;
            }
        }
    }
    __syncthreads();
    // triangle scatter
#pragma unroll
    for (int i = 0; i < 9; ++i) {
        int t = lane + 64 * i;
        if (t < 560) {
            int e_ij = te1[t], e_ik = te2[t], e_jk = te3[t], jm = tj_[t];
            float t2 = 2.f * W1[wave][e_ij] * W1[wave][e_jk] * W1[wave][e_ik];
            atomicAdd(&A1[wave][jm][e_ij], t2);
            atomicAdd(&A1[wave][jm][e_ik], -t2);
            atomicAdd(&A1[wave][jm][e_jk], t2);
        }
    }
    __syncthreads();
    // outputs: L0, G, g
    float* mb = Mbuf + (size_t)b * 1536;
#pragma unroll
    for (int j = 0; j < 4; ++j) {
        int p = j * 64 + lane;
        int k = p >> 4, m = p & 15;
        float gsum = 0.f;
#pragma unroll
        for (int o = 0; o < 16; ++o)
            if (o != m) gsum += A1[wave][k][fmat[m][o]];
        float l0;
        if (k == m) {
            float dsum = 0.f;
#pragma unroll
            for (int o = 0; o < 16; ++o)
                if (o != k) dsum += W1[wave][fmat[k][o]];
            l0 = dsum + TAU;
        } else {
            l0 = -W1[wave][fmat[k][m]];
        }
        mb[s * 256 + p] = l0;
        mb[768 + s * 256 + p] = gsum;
    }
    if (lane < 16) {
        const float4* ap = (const float4*)&A1[wave][lane][0];
        float p = 0.f;
#pragma unroll
        for (int f4 = 0; f4 < 30; ++f4) {
            float4 v = ap[f4];
            p += v.x + v.y + v.z + v.w;
        }
        gbuf[b * 48 + lane * 3 + s] = p;
    }
}

// ---------------------------------------------------------------------------
// gemm cores
// ---------------------------------------------------------------------------
__device__ __forceinline__ void gemm128(const ushort_t* __restrict__ A,
                                        const ushort_t* __restrict__ Bt,
                                        int Kdim, int m0, int n0,
                                        f32x4 acc[4][4],
                                        ushort_t (*As)[32], ushort_t (*Bs)[32]) {
    const int tid = threadIdx.x;
    const int wave = tid >> 6, lane = tid & 63;
    const int lq = lane >> 4, lr = lane & 15;
    const int wm = wave >> 1, wn = wave & 1;
    const int r = tid >> 2, ca = (tid & 3) << 3;
    const ushort_t* Ag0 = A + (size_t)(m0 + r) * Kdim + ca;
    const ushort_t* Ag1 = A + (size_t)(m0 + 64 + r) * Kdim + ca;
    const ushort_t* Bg0 = Bt + (size_t)(n0 + r) * Kdim + ca;
    const ushort_t* Bg1 = Bt + (size_t)(n0 + 64 + r) * Kdim + ca;
    char* AsD0 = (char*)As + wave * 1024;
    char* AsD1 = (char*)As + 4096 + wave * 1024;
    char* BsD0 = (char*)Bs + wave * 1024;
    char* BsD1 = (char*)Bs + 4096 + wave * 1024;
    for (int kt = 0; kt < Kdim; kt += 32) {
        __syncthreads();
        glds16(Ag0 + kt, AsD0);
        glds16(Ag1 + kt, AsD1);
        glds16(Bg0 + kt, BsD0);
        glds16(Bg1 + kt, BsD1);
        __syncthreads();
        short8 af[4], bfr[4];
#pragma unroll
        for (int i = 0; i < 4; ++i) af[i] = *(const short8*)&As[wm * 64 + i * 16 + lr][lq * 8];
#pragma unroll
        for (int j = 0; j < 4; ++j) bfr[j] = *(const short8*)&Bs[wn * 64 + j * 16 + lr][lq * 8];
#pragma unroll
        for (int i = 0; i < 4; ++i)
#pragma unroll
            for (int j = 0; j < 4; ++j)
                acc[i][j] = __builtin_amdgcn_mfma_f32_16x16x32_bf16(af[i], bfr[j], acc[i][j], 0, 0, 0);
    }
}

__device__ __forceinline__ void gemm64(const ushort_t* __restrict__ A,
                                       const ushort_t* __restrict__ Bt,
                                       int Kdim, int m0, int n0,
                                       f32x4 acc[2][4],
                                       ushort_t (*As)[32], ushort_t (*Bs)[32]) {
    const int tid = threadIdx.x;
    const int wave = tid >> 6, lane = tid & 63;
    const int lq = lane >> 4, lr = lane & 15;
    const int wm = wave >> 1, wn = wave & 1;
    const int r = tid >> 2, ca = (tid & 3) << 3;
    const ushort_t* Ag = A + (size_t)(m0 + r) * Kdim + ca;
    const ushort_t* Bg0 = Bt + (size_t)(n0 + r) * Kdim + ca;
    const ushort_t* Bg1 = Bt + (size_t)(n0 + 64 + r) * Kdim + ca;
    char* AsD = (char*)As + wave * 1024;
    char* Bs0D = (char*)Bs + wave * 1024;
    char* Bs1D = (char*)Bs + 4096 + wave * 1024;
    for (int kt = 0; kt < Kdim; kt += 32) {
        __syncthreads();
        glds16(Ag + kt, AsD);
        glds16(Bg0 + kt, Bs0D);
        glds16(Bg1 + kt, Bs1D);
        __syncthreads();
        short8 af[2], bfr[4];
#pragma unroll
        for (int i = 0; i < 2; ++i) af[i] = *(const short8*)&As[wm * 32 + i * 16 + lr][lq * 8];
#pragma unroll
        for (int j = 0; j < 4; ++j) bfr[j] = *(const short8*)&Bs[wn * 64 + j * 16 + lr][lq * 8];
#pragma unroll
        for (int i = 0; i < 2; ++i)
#pragma unroll
            for (int j = 0; j < 4; ++j)
                acc[i][j] = __builtin_amdgcn_mfma_f32_16x16x32_bf16(af[i], bfr[j], acc[i][j], 0, 0, 0);
    }
}

// kY: Y = xn @ Wk' (M=16384, N=1536, K=256), 128x128 tiles, grid (128,12)
__global__ __launch_bounds__(256) void kY_gemm(const ushort_t* __restrict__ xn,
                                               const ushort_t* __restrict__ WkT,
                                               ushort_t* __restrict__ Y) {
    __shared__ ushort_t As[128][32];
    __shared__ ushort_t Bs[128][32];
    const int tid = threadIdx.x;
    const int m0 = blockIdx.x * 128, n0 = blockIdx.y * 128;
    f32x4 acc[4][4] = {};
    gemm128(xn, WkT, 256, m0, n0, acc, As, Bs);
    const int wave = tid >> 6, lane = tid & 63, lq = lane >> 4, lr = lane & 15;
    const int wm = wave >> 1, wn = wave & 1;
#pragma unroll
    for (int i = 0; i < 4; ++i)
#pragma unroll
        for (int j = 0; j < 4; ++j) {
            int n = n0 + wn * 64 + j * 16 + lr;
#pragma unroll
            for (int v = 0; v < 4; ++v) {
                int rg = m0 + wm * 64 + i * 16 + lq * 4 + v;
                Y[(size_t)rg * 1536 + n] = f2bf(acc[i][j][v]);
            }
        }
}

// kZ: per-b Z = sum_rt M_rt @ Y_rt; epilogue x'=x+Z+cv+sum g*beWo; fused LN2->h
__global__ __launch_bounds__(256) void kZ_apply(
    const ushort_t* __restrict__ Y, const float* __restrict__ Mbuf,
    const float* __restrict__ xin, const float* __restrict__ bo,
    const float* __restrict__ cvpart, const float* __restrict__ beWo,
    const float* __restrict__ gbuf, const float* __restrict__ g2,
    const float* __restrict__ b2, float* __restrict__ xp,
    ushort_t* __restrict__ h) {
    __shared__ __align__(16) char YsRaw[49152];
    ushort_t* Ys = (ushort_t*)YsRaw;
    float (*xpS)[260] = (float(*)[260])YsRaw;
    __shared__ float Ms[1536];
    __shared__ float gS[48];
    __shared__ float mrS[16][2];
    const int b = blockIdx.x, tid = threadIdx.x;
    const int wave = tid >> 6, lane = tid & 63;
    const char* Ybc = (const char*)(Y + (size_t)b * 24576);
#pragma unroll
    for (int it = 0; it < 12; ++it) {
        int base = it * 4096 + wave * 1024;
        glds16(Ybc + base + lane * 16, YsRaw + base);
    }
#pragma unroll
    for (int i = 0; i < 6; ++i) Ms[tid + i * 256] = Mbuf[(size_t)b * 1536 + tid + i * 256];
    if (tid < 48) gS[tid] = gbuf[b * 48 + tid];
    __syncthreads();

    const int q = tid;
    float yv[96];
#pragma unroll
    for (int rt = 0; rt < 6; ++rt)
#pragma unroll
        for (int l = 0; l < 16; ++l)
            yv[rt * 16 + l] = bf2f(Ys[l * 1536 + rt * 256 + q]);

    float accv[16];
#pragma unroll
    for (int k = 0; k < 16; ++k) {
        float a = 0.f;
#pragma unroll
        for (int rt = 0; rt < 6; ++rt) {
            const float4* mp = (const float4*)&Ms[rt * 256 + k * 16];
            float4 m0 = mp[0], m1 = mp[1], m2 = mp[2], m3 = mp[3];
            const float* yp = &yv[rt * 16];
            a += m0.x * yp[0] + m0.y * yp[1] + m0.z * yp[2] + m0.w * yp[3]
               + m1.x * yp[4] + m1.y * yp[5] + m1.z * yp[6] + m1.w * yp[7]
               + m2.x * yp[8] + m2.y * yp[9] + m2.z * yp[10] + m2.w * yp[11]
               + m3.x * yp[12] + m3.y * yp[13] + m3.z * yp[14] + m3.w * yp[15];
        }
        accv[k] = a;
    }

    float cv = bo[q] + TAU * (cvpart[q] + cvpart[256 + q] + cvpart[512 + q]);
    float bw0 = beWo[q], bw1 = beWo[256 + q], bw2 = beWo[512 + q];
    const float* xb2 = xin + (size_t)b * 4096;
    float* xpb = xp + (size_t)b * 4096;
    float xpv[16];
#pragma unroll
    for (int k = 0; k < 16; ++k) {
        xpv[k] = accv[k] + xb2[k * 256 + q] + cv +
                 gS[k * 3] * bw0 + gS[k * 3 + 1] * bw1 + gS[k * 3 + 2] * bw2;
        xpb[k * 256 + q] = xpv[k];
    }
    __syncthreads();
#pragma unroll
    for (int k = 0; k < 16; ++k) xpS[k][q] = xpv[k];
    __syncthreads();

    {
        const int kk = tid >> 4, c = tid & 15;
        float s = 0.f;
#pragma unroll
        for (int j = 0; j < 16; ++j) s += xpS[kk][c + 16 * j];
        for (int off = 8; off; off >>= 1) s += __shfl_down(s, off, 16);
        float mean = __shfl(s, 0, 16) * (1.f / 256.f);
        float vs = 0.f;
#pragma unroll
        for (int j = 0; j < 16; ++j) { float d = xpS[kk][c + 16 * j] - mean; vs += d * d; }
        for (int off = 8; off; off >>= 1) vs += __shfl_down(vs, off, 16);
        float rstd = rsqrtf(__shfl(vs, 0, 16) * (1.f / 256.f) + LN_EPS);
        if (c == 0) { mrS[kk][0] = mean; mrS[kk][1] = rstd; }
    }
    __syncthreads();
    ushort_t* hb = h + (size_t)b * 4096;
    const float g2q = g2[q], b2q = b2[q];
#pragma unroll
    for (int k = 0; k < 16; ++k) {
        float m = mrS[k][0], r = mrS[k][1];
        hb[k * 256 + q] = f2bf((xpS[k][q] - m) * r * g2q + b2q);
    }
}

// K3: F1g = gelu(h @ Wf1 + bf1), 128x128, grid (128,8)
__global__ __launch_bounds__(256) void k3_gemm(const ushort_t* __restrict__ h,
                                               const ushort_t* __restrict__ Wf1T,
                                               const float* __restrict__ bf1,
                                               ushort_t* __restrict__ F1g) {
    __shared__ ushort_t As[128][32];
    __shared__ ushort_t Bs[128][32];
    const int tid = threadIdx.x;
    const int m0 = blockIdx.x * 128, n0 = blockIdx.y * 128;
    f32x4 acc[4][4] = {};
    gemm128(h, Wf1T, 256, m0, n0, acc, As, Bs);
    const int wave = tid >> 6, lane = tid & 63, lq = lane >> 4, lr = lane & 15;
    const int wm = wave >> 1, wn = wave & 1;
#pragma unroll
    for (int i = 0; i < 4; ++i)
#pragma unroll
        for (int j = 0; j < 4; ++j) {
            int n = n0 + wn * 64 + j * 16 + lr;
            float bn = bf1[n];
#pragma unroll
            for (int v = 0; v < 4; ++v) {
                int rg = m0 + wm * 64 + i * 16 + lq * 4 + v;
                float u = acc[i][j][v] + bn;
                float gl = 0.5f * u * (1.f + erff(u * 0.70710678118f));
                F1g[(size_t)rg * 1024 + n] = f2bf(gl);
            }
        }
}

// K4: out = xp + F1g @ Wf2 + bf2, 64x128, grid (256,2)
__global__ __launch_bounds__(256) void k4_gemm(const ushort_t* __restrict__ F1g,
                                               const ushort_t* __restrict__ Wf2T,
                                               const float* __restrict__ bf2,
                                               const float* __restrict__ xp,
                                               float* __restrict__ out) {
    __shared__ ushort_t As[64][32];
    __shared__ ushort_t Bs[128][32];
    const int tid = threadIdx.x;
    const int m0 = blockIdx.x * 64, n0 = blockIdx.y * 128;
    f32x4 acc[2][4] = {};
    gemm64(F1g, Wf2T, 1024, m0, n0, acc, As, Bs);
    const int wave = tid >> 6, lane = tid & 63, lq = lane >> 4, lr = lane & 15;
    const int wm = wave >> 1, wn = wave & 1;
#pragma unroll
    for (int i = 0; i < 2; ++i)
#pragma unroll
        for (int j = 0; j < 4; ++j) {
            int n = n0 + wn * 64 + j * 16 + lr;
            float bn = bf2[n];
#pragma unroll
            for (int v = 0; v < 4; ++v) {
                size_t idx = (size_t)(m0 + wm * 32 + i * 16 + lq * 4 + v) * 256 + n;
                out[idx] = xp[idx] + acc[i][j][v] + bn;
            }
        }
}

extern "C" void kernel_launch(void* const* d_in, const int* in_sizes, int n_in,
                              void* d_out, int out_size, void* d_ws, size_t ws_size,
                              hipStream_t stream) {
    const float* x = (const float*)d_in[0];
    const float* mask = (const float*)d_in[1];
    const float* Wg = (const float*)d_in[2];
    const float* bg = (const float*)d_in[3];
    const float* ls = (const float*)d_in[4];
    const float* Wv = (const float*)d_in[5];
    const float* bv = (const float*)d_in[6];
    const float* We = (const float*)d_in[7];
    const float* be = (const float*)d_in[8];
    const float* Wo = (const float*)d_in[9];
    const float* bo = (const float*)d_in[10];
    const float* g1 = (const float*)d_in[11];
    const float* b1 = (const float*)d_in[12];
    const float* g2 = (const float*)d_in[13];
    const float* b2 = (const float*)d_in[14];
    const float* Wf1 = (const float*)d_in[15];
    const float* bf1 = (const float*)d_in[16];
    const float* Wf2 = (const float*)d_in[17];
    const float* bf2 = (const float*)d_in[18];
    float* out = (float*)d_out;

    char* ws = (char*)d_ws;
    ushort_t* Y = (ushort_t*)(ws);                      // 50,331,648
    ushort_t* F1g = (ushort_t*)(ws);                    // 33,554,432 (alias: Y dead after kZ)
    ushort_t* WkT = (ushort_t*)(ws + 50331648);         //    786,432
    ushort_t* Wf1T = (ushort_t*)(ws + 51118080);        //    524,288
    ushort_t* Wf2T = (ushort_t*)(ws + 51642368);        //    524,288
    float* cvpart = (float*)(ws + 52166656);            //      3,072
    float* beWo = (float*)(ws + 52169728);              //      3,072
    float* gbuf = (float*)(ws + 52172800);              //    196,608
    float* xp = (float*)(ws + 52369408);                // 16,777,216
    float* Dsqbuf = (float*)(ws + 52369408);            //  1,048,576 (alias: dead before kZ writes xp)
    ushort_t* h = (ushort_t*)(ws + 69146624);           //  8,388,608
    ushort_t* xnbuf = (ushort_t*)(ws + 77535232);       //  8,388,608
    float* Wtmp = (float*)(ws + 77535232);              //  1,572,864 (alias: dead before kLN1P)
    float* Mbuf = (float*)(ws + 85923840);              //  6,291,456  -> end 92,215,296

    kw_fuse<<<dim3(65, 6), dim3(256), 0, stream>>>(Wv, We, Wo, bv, be, Wtmp, cvpart, beWo);
    kw_trans<<<dim3(224), dim3(256), 0, stream>>>(Wtmp, Wf1, Wf2, WkT, Wf1T, Wf2T);
    kLN1P<<<dim3(1024), dim3(256), 0, stream>>>(x, mask, Wg, bg, g1, b1, xnbuf, Dsqbuf);
    k1c_graph<<<dim3(768), dim3(256), 0, stream>>>(Dsqbuf, mask, ls, Mbuf, gbuf);
    kY_gemm<<<dim3(128, 12), dim3(256), 0, stream>>>(xnbuf, WkT, Y);
    kZ_apply<<<dim3(1024), dim3(256), 0, stream>>>(Y, Mbuf, x, bo, cvpart, beWo, gbuf, g2, b2, xp, h);
    k3_gemm<<<dim3(128, 8), dim3(256), 0, stream>>>(h, Wf1T, bf1, F1g);
    k4_gemm<<<dim3(256, 2), dim3(256), 0, stream>>>(F1g, Wf2T, bf2, xp, out);
}

// Round 5
// 235.616 us; speedup vs baseline: 1.5711x; 1.1462x over previous
//
#include <hip/hip_runtime.h>
#include <hip/hip_bf16.h>
#include <cstdint>
#include <cstddef>

#define TAU 1e-4f
#define LN_EPS 1e-5f

typedef unsigned short ushort_t;
typedef unsigned int uint_t;
typedef __attribute__((ext_vector_type(8))) short short8;
typedef __attribute__((ext_vector_type(4))) float f32x4;

__device__ __forceinline__ ushort_t f2bf(float f) {
    union { float f; unsigned int u; } c; c.f = f;
    unsigned int r = (c.u + 0x7fffu + ((c.u >> 16) & 1u)) >> 16;
    return (ushort_t)r;
}
__device__ __forceinline__ float bf2f(ushort_t u) {
    union { unsigned int u; float f; } c; c.u = ((unsigned int)u) << 16;
    return c.f;
}
__device__ __forceinline__ void glds16(const void* g, void* l) {
    __builtin_amdgcn_global_load_lds((const __attribute__((address_space(1))) unsigned int*)g,
                                     (__attribute__((address_space(3))) unsigned int*)l,
                                     16, 0, 0);
}

// ---------------------------------------------------------------------------
// kprep: all weight prep in ONE kernel. grid 518:
//   id <384 : Wcat fuse -> WkT (bf16, transposed write), 64 q-blocks x 6 (half,s)
//   id <390 : bias vectors (cvpart / beWo)
//   id <454 : Wf1 (256x1024) -> Wf1T (1024x256) bf16, 64 tiles
//   else    : Wf2 (1024x256) -> Wf2T (256x1024) bf16, 64 tiles
// ---------------------------------------------------------------------------
__global__ __launch_bounds__(256) void kprep(
    const float* __restrict__ Wv, const float* __restrict__ We,
    const float* __restrict__ Wo, const float* __restrict__ bv,
    const float* __restrict__ be, const float* __restrict__ Wf1,
    const float* __restrict__ Wf2, ushort_t* __restrict__ WkT,
    ushort_t* __restrict__ Wf1T, ushort_t* __restrict__ Wf2T,
    float* __restrict__ cvpart, float* __restrict__ beWo) {
    __shared__ __align__(16) float S[64 * 65];
    const int tid = threadIdx.x;
    const int id = blockIdx.x;
    if (id < 384) {
        float (*rowS)[256] = (float(*)[256])S;
        const int q0 = (id & 63) * 4;
        const int w = id >> 6;
        const int half = w / 3, s = w - half * 3;
        const float* src = half ? We : Wv;
#pragma unroll
        for (int r = 0; r < 4; ++r)
            rowS[r][tid] = src[(size_t)(q0 + r) * 768 + s * 256 + tid];
        __syncthreads();
        const float* wo = Wo + (size_t)(half * 768 + s * 256) * 256 + tid;
        float a0 = 0.f, a1 = 0.f, a2 = 0.f, a3 = 0.f;
        for (int d = 0; d < 256; ++d) {
            float wv = wo[(size_t)d * 256];
            a0 += rowS[0][d] * wv; a1 += rowS[1][d] * wv;
            a2 += rowS[2][d] * wv; a3 += rowS[3][d] * wv;
        }
        const int rt = half * 3 + s;
        ushort4 pk;
        pk.x = f2bf(a0); pk.y = f2bf(a1); pk.z = f2bf(a2); pk.w = f2bf(a3);
        *(ushort4*)&WkT[(size_t)(rt * 256 + tid) * 256 + q0] = pk;
    } else if (id < 390) {
        const int w = id - 384;
        const int half = w / 3, s = w - half * 3;
        const float* vec = half ? be : bv;
        S[tid] = vec[s * 256 + tid];
        __syncthreads();
        const float* wo = Wo + (size_t)(half * 768 + s * 256) * 256 + tid;
        float acc = 0.f;
        for (int d = 0; d < 256; ++d) acc += S[d] * wo[(size_t)d * 256];
        if (half) beWo[s * 256 + tid] = acc;
        else cvpart[s * 256 + tid] = acc;
    } else {
        float (*tS)[65] = (float(*)[65])S;
        const float* src; ushort_t* dst;
        int sr0, sc0, ss, dr0, dc0, ds_;
        if (id < 454) {
            int t = id - 390; int ki = t & 3, ni = t >> 2;
            src = Wf1; ss = 1024; sr0 = ki * 64; sc0 = ni * 64;
            dst = Wf1T; ds_ = 256; dr0 = ni * 64; dc0 = ki * 64;
        } else {
            int t = id - 454; int ki = t >> 2, ni = t & 3;
            src = Wf2; ss = 256; sr0 = ki * 64; sc0 = ni * 64;
            dst = Wf2T; ds_ = 1024; dr0 = ni * 64; dc0 = ki * 64;
        }
        const int rl = tid >> 6, cl = tid & 63;
#pragma unroll
        for (int p = 0; p < 16; ++p) {
            int r = p * 4 + rl;
            tS[r][cl] = src[(size_t)(sr0 + r) * ss + sc0 + cl];
        }
        __syncthreads();
#pragma unroll
        for (int p = 0; p < 16; ++p) {
            int r = p * 4 + rl;
            dst[(size_t)(dr0 + r) * ds_ + dc0 + cl] = f2bf(tS[cl][r]);
        }
    }
}

// ---------------------------------------------------------------------------
// kLN1G: per-b LN1 -> xn (bf16), P, Dsq, and the WHOLE graph algebra via the
// diagonal-T identity: G_up[k][m] = 4*[m==k]*T[k],
//   T[k] = sum_{i<k} Wh[i][k] * (sum_{j>k} Wh[k][j]*Wh[i][j])
// G_down = closed form in mask; g = row-sum(G)/2. No A1 matrix, no atomics.
// ---------------------------------------------------------------------------
__global__ __launch_bounds__(256) void kLN1G(
    const float* __restrict__ xg, const float* __restrict__ maskg,
    const float* __restrict__ Wg, const float* __restrict__ bg,
    const float* __restrict__ ls, const float* __restrict__ g1,
    const float* __restrict__ b1, ushort_t* __restrict__ xnbuf,
    float* __restrict__ Mbuf, float* __restrict__ gbuf) {
    __shared__ float XS[16][260];
    __shared__ __align__(16) float WB[16 * 260];   // phase A: WgT; phase B: Dsq/Wh/T
    __shared__ float Pl[16][17];
    __shared__ float dotm[16][17];
    __shared__ float mk[16];
    float (*WgT)[260] = (float(*)[260])WB;
    float (*DsqS)[17] = (float(*)[17])WB;                    // 272 floats
    float (*Wh)[16][17] = (float(*)[16][17])(WB + 272);      // 816 floats
    float* Ts = WB + 1088;                                   // 48 floats
    const int b = blockIdx.x;
    const int tid = threadIdx.x;

    const float* xb = xg + (size_t)b * 4096;
#pragma unroll
    for (int i = 0; i < 4; ++i) {
        int idx = tid * 4 + i * 1024;
        int k = idx >> 8, c = idx & 255;
        float4 v = *(const float4*)&xb[idx];
        XS[k][c] = v.x; XS[k][c + 1] = v.y; XS[k][c + 2] = v.z; XS[k][c + 3] = v.w;
    }
    {
        const float4* wgp = (const float4*)(Wg + tid * 16);
        float4 w0 = wgp[0], w1 = wgp[1], w2 = wgp[2], w3 = wgp[3];
        WgT[0][tid] = w0.x; WgT[1][tid] = w0.y; WgT[2][tid] = w0.z; WgT[3][tid] = w0.w;
        WgT[4][tid] = w1.x; WgT[5][tid] = w1.y; WgT[6][tid] = w1.z; WgT[7][tid] = w1.w;
        WgT[8][tid] = w2.x; WgT[9][tid] = w2.y; WgT[10][tid] = w2.z; WgT[11][tid] = w2.w;
        WgT[12][tid] = w3.x; WgT[13][tid] = w3.y; WgT[14][tid] = w3.z; WgT[15][tid] = w3.w;
    }
    if (tid < 16) mk[tid] = maskg[b * 16 + tid];
    __syncthreads();

    // LN1
    {
        const int k = tid >> 4, c = tid & 15;
        float s = 0.f;
#pragma unroll
        for (int j = 0; j < 16; ++j) s += XS[k][c + 16 * j];
        for (int off = 8; off; off >>= 1) s += __shfl_down(s, off, 16);
        float mean = __shfl(s, 0, 16) * (1.f / 256.f);
        float vs = 0.f;
#pragma unroll
        for (int j = 0; j < 16; ++j) { float d = XS[k][c + 16 * j] - mean; vs += d * d; }
        for (int off = 8; off; off >>= 1) vs += __shfl_down(vs, off, 16);
        float rstd = rsqrtf(__shfl(vs, 0, 16) * (1.f / 256.f) + LN_EPS);
#pragma unroll
        for (int j = 0; j < 16; ++j) {
            int cc = c + 16 * j;
            XS[k][cc] = (XS[k][cc] - mean) * rstd * g1[cc] + b1[cc];
        }
    }
    __syncthreads();

    // xn (bf16, packed pairs)
#pragma unroll
    for (int i = 0; i < 8; ++i) {
        int idx2 = tid * 2 + i * 512;
        int k = idx2 >> 8, c = idx2 & 255;
        uint_t v = (uint_t)f2bf(XS[k][c]) | ((uint_t)f2bf(XS[k][c + 1]) << 16);
        *(uint_t*)&xnbuf[(size_t)b * 4096 + idx2] = v;
    }

    // P[k][c]
    {
        const int k = tid >> 4, c = tid & 15;
        float acc = bg[c];
#pragma unroll
        for (int q4 = 0; q4 < 64; ++q4) {
            float4 wv = *(const float4*)&WgT[c][q4 * 4];
            float4 xv = *(const float4*)&XS[k][q4 * 4];
            acc += wv.x * xv.x + wv.y * xv.y + wv.z * xv.z + wv.w * xv.w;
        }
        Pl[k][c] = acc;
    }
    __syncthreads();   // WgT dead from here; WB reused
    const int k = tid >> 4, m = tid & 15;
    {
        float d = 0.f;
#pragma unroll
        for (int c = 0; c < 16; ++c) d += Pl[k][c] * Pl[m][c];
        dotm[k][m] = d;
    }
    __syncthreads();
    {
        float v = dotm[k][k] + dotm[m][m] - 2.f * dotm[k][m];
        DsqS[k][m] = fmaxf(v, 0.f) * mk[k] * mk[m];
    }
    // Wh (reads own DsqS entry — no sync needed)
    {
        float d = DsqS[k][m];
        float mm = mk[k] * mk[m];
#pragma unroll
        for (int s = 0; s < 3; ++s) {
            float i2 = 1.f / (2.f * expf(2.f * ls[s]) + 1e-8f);
            Wh[s][k][m] = (k == m) ? 0.f : expf(-d * i2) * mm;
        }
    }
    __syncthreads();
    // T[s][j] = sum_{i<j} Wh[i][j] * sum_{jj>j} Wh[j][jj]*Wh[i][jj]
    if (tid < 48) {
        int s = tid >> 4, j = tid & 15;
        float t = 0.f;
        for (int i = 0; i < j; ++i) {
            float d = 0.f;
            for (int jj = j + 1; jj < 16; ++jj) d += Wh[s][j][jj] * Wh[s][i][jj];
            t += Wh[s][i][j] * d;
        }
        Ts[s * 16 + j] = t;
    }
    __syncthreads();
    // G_down closed form (s-independent), then per-s outputs
    float gd = 0.f;
#pragma unroll
    for (int o = 0; o < 16; ++o) {
        if (o == m) continue;
        int u = o < m ? o : m, v = o < m ? m : o;
        float gu = (u == k) ? (float)(2 * k - 15) : ((u > k) ? 1.f : -1.f);
        float gv = (v == k) ? (float)(2 * k - 15) : ((v > k) ? 1.f : -1.f);
        gd += -gu * mk[u] + gv * mk[v];
        if (u == k || v == k) gd += TAU;
    }
    float* mb = Mbuf + (size_t)b * 1536;
#pragma unroll
    for (int s = 0; s < 3; ++s) {
        float rs = 0.f;
#pragma unroll
        for (int o = 0; o < 16; ++o) rs += Wh[s][k][o];
        float l0 = (k == m) ? (rs + TAU) : -Wh[s][k][m];
        float G = gd + ((k == m) ? 4.f * Ts[s * 16 + k] : 0.f);
        mb[s * 256 + tid] = l0;
        mb[768 + s * 256 + tid] = G;
        float gg = G;
        for (int off = 8; off; off >>= 1) gg += __shfl_down(gg, off, 16);
        if (m == 0) gbuf[b * 48 + k * 3 + s] = 0.5f * gg;
    }
}

// ---------------------------------------------------------------------------
// gemm cores (unchanged from round 4)
// ---------------------------------------------------------------------------
__device__ __forceinline__ void gemm128(const ushort_t* __restrict__ A,
                                        const ushort_t* __restrict__ Bt,
                                        int Kdim, int m0, int n0,
                                        f32x4 acc[4][4],
                                        ushort_t (*As)[32], ushort_t (*Bs)[32]) {
    const int tid = threadIdx.x;
    const int wave = tid >> 6, lane = tid & 63;
    const int lq = lane >> 4, lr = lane & 15;
    const int wm = wave >> 1, wn = wave & 1;
    const int r = tid >> 2, ca = (tid & 3) << 3;
    const ushort_t* Ag0 = A + (size_t)(m0 + r) * Kdim + ca;
    const ushort_t* Ag1 = A + (size_t)(m0 + 64 + r) * Kdim + ca;
    const ushort_t* Bg0 = Bt + (size_t)(n0 + r) * Kdim + ca;
    const ushort_t* Bg1 = Bt + (size_t)(n0 + 64 + r) * Kdim + ca;
    char* AsD0 = (char*)As + wave * 1024;
    char* AsD1 = (char*)As + 4096 + wave * 1024;
    char* BsD0 = (char*)Bs + wave * 1024;
    char* BsD1 = (char*)Bs + 4096 + wave * 1024;
    for (int kt = 0; kt < Kdim; kt += 32) {
        __syncthreads();
        glds16(Ag0 + kt, AsD0);
        glds16(Ag1 + kt, AsD1);
        glds16(Bg0 + kt, BsD0);
        glds16(Bg1 + kt, BsD1);
        __syncthreads();
        short8 af[4], bfr[4];
#pragma unroll
        for (int i = 0; i < 4; ++i) af[i] = *(const short8*)&As[wm * 64 + i * 16 + lr][lq * 8];
#pragma unroll
        for (int j = 0; j < 4; ++j) bfr[j] = *(const short8*)&Bs[wn * 64 + j * 16 + lr][lq * 8];
#pragma unroll
        for (int i = 0; i < 4; ++i)
#pragma unroll
            for (int j = 0; j < 4; ++j)
                acc[i][j] = __builtin_amdgcn_mfma_f32_16x16x32_bf16(af[i], bfr[j], acc[i][j], 0, 0, 0);
    }
}

__device__ __forceinline__ void gemm64(const ushort_t* __restrict__ A,
                                       const ushort_t* __restrict__ Bt,
                                       int Kdim, int m0, int n0,
                                       f32x4 acc[2][4],
                                       ushort_t (*As)[32], ushort_t (*Bs)[32]) {
    const int tid = threadIdx.x;
    const int wave = tid >> 6, lane = tid & 63;
    const int lq = lane >> 4, lr = lane & 15;
    const int wm = wave >> 1, wn = wave & 1;
    const int r = tid >> 2, ca = (tid & 3) << 3;
    const ushort_t* Ag = A + (size_t)(m0 + r) * Kdim + ca;
    const ushort_t* Bg0 = Bt + (size_t)(n0 + r) * Kdim + ca;
    const ushort_t* Bg1 = Bt + (size_t)(n0 + 64 + r) * Kdim + ca;
    char* AsD = (char*)As + wave * 1024;
    char* Bs0D = (char*)Bs + wave * 1024;
    char* Bs1D = (char*)Bs + 4096 + wave * 1024;
    for (int kt = 0; kt < Kdim; kt += 32) {
        __syncthreads();
        glds16(Ag + kt, AsD);
        glds16(Bg0 + kt, Bs0D);
        glds16(Bg1 + kt, Bs1D);
        __syncthreads();
        short8 af[2], bfr[4];
#pragma unroll
        for (int i = 0; i < 2; ++i) af[i] = *(const short8*)&As[wm * 32 + i * 16 + lr][lq * 8];
#pragma unroll
        for (int j = 0; j < 4; ++j) bfr[j] = *(const short8*)&Bs[wn * 64 + j * 16 + lr][lq * 8];
#pragma unroll
        for (int i = 0; i < 2; ++i)
#pragma unroll
            for (int j = 0; j < 4; ++j)
                acc[i][j] = __builtin_amdgcn_mfma_f32_16x16x32_bf16(af[i], bfr[j], acc[i][j], 0, 0, 0);
    }
}

// kY: Y = xn @ Wk' (M=16384, N=1536, K=256), 128x128 tiles, grid (128,12)
__global__ __launch_bounds__(256) void kY_gemm(const ushort_t* __restrict__ xn,
                                               const ushort_t* __restrict__ WkT,
                                               ushort_t* __restrict__ Y) {
    __shared__ ushort_t As[128][32];
    __shared__ ushort_t Bs[128][32];
    const int tid = threadIdx.x;
    const int m0 = blockIdx.x * 128, n0 = blockIdx.y * 128;
    f32x4 acc[4][4] = {};
    gemm128(xn, WkT, 256, m0, n0, acc, As, Bs);
    const int wave = tid >> 6, lane = tid & 63, lq = lane >> 4, lr = lane & 15;
    const int wm = wave >> 1, wn = wave & 1;
#pragma unroll
    for (int i = 0; i < 4; ++i)
#pragma unroll
        for (int j = 0; j < 4; ++j) {
            int n = n0 + wn * 64 + j * 16 + lr;
#pragma unroll
            for (int v = 0; v < 4; ++v) {
                int rg = m0 + wm * 64 + i * 16 + lq * 4 + v;
                Y[(size_t)rg * 1536 + n] = f2bf(acc[i][j][v]);
            }
        }
}

// kZ: per-b Z = sum_rt M_rt @ Y_rt; epilogue x'=x+Z+cv+sum g*beWo; fused LN2->h
__global__ __launch_bounds__(256) void kZ_apply(
    const ushort_t* __restrict__ Y, const float* __restrict__ Mbuf,
    const float* __restrict__ xin, const float* __restrict__ bo,
    const float* __restrict__ cvpart, const float* __restrict__ beWo,
    const float* __restrict__ gbuf, const float* __restrict__ g2,
    const float* __restrict__ b2, float* __restrict__ xp,
    ushort_t* __restrict__ h) {
    __shared__ __align__(16) char YsRaw[49152];
    ushort_t* Ys = (ushort_t*)YsRaw;
    float (*xpS)[260] = (float(*)[260])YsRaw;
    __shared__ float Ms[1536];
    __shared__ float gS[48];
    __shared__ float mrS[16][2];
    const int b = blockIdx.x, tid = threadIdx.x;
    const int wave = tid >> 6, lane = tid & 63;
    const char* Ybc = (const char*)(Y + (size_t)b * 24576);
#pragma unroll
    for (int it = 0; it < 12; ++it) {
        int base = it * 4096 + wave * 1024;
        glds16(Ybc + base + lane * 16, YsRaw + base);
    }
#pragma unroll
    for (int i = 0; i < 6; ++i) Ms[tid + i * 256] = Mbuf[(size_t)b * 1536 + tid + i * 256];
    if (tid < 48) gS[tid] = gbuf[b * 48 + tid];
    __syncthreads();

    const int q = tid;
    float yv[96];
#pragma unroll
    for (int rt = 0; rt < 6; ++rt)
#pragma unroll
        for (int l = 0; l < 16; ++l)
            yv[rt * 16 + l] = bf2f(Ys[l * 1536 + rt * 256 + q]);

    float accv[16];
#pragma unroll
    for (int k = 0; k < 16; ++k) {
        float a = 0.f;
#pragma unroll
        for (int rt = 0; rt < 6; ++rt) {
            const float4* mp = (const float4*)&Ms[rt * 256 + k * 16];
            float4 m0 = mp[0], m1 = mp[1], m2 = mp[2], m3 = mp[3];
            const float* yp = &yv[rt * 16];
            a += m0.x * yp[0] + m0.y * yp[1] + m0.z * yp[2] + m0.w * yp[3]
               + m1.x * yp[4] + m1.y * yp[5] + m1.z * yp[6] + m1.w * yp[7]
               + m2.x * yp[8] + m2.y * yp[9] + m2.z * yp[10] + m2.w * yp[11]
               + m3.x * yp[12] + m3.y * yp[13] + m3.z * yp[14] + m3.w * yp[15];
        }
        accv[k] = a;
    }

    float cv = bo[q] + TAU * (cvpart[q] + cvpart[256 + q] + cvpart[512 + q]);
    float bw0 = beWo[q], bw1 = beWo[256 + q], bw2 = beWo[512 + q];
    const float* xb2 = xin + (size_t)b * 4096;
    float* xpb = xp + (size_t)b * 4096;
    float xpv[16];
#pragma unroll
    for (int k = 0; k < 16; ++k) {
        xpv[k] = accv[k] + xb2[k * 256 + q] + cv +
                 gS[k * 3] * bw0 + gS[k * 3 + 1] * bw1 + gS[k * 3 + 2] * bw2;
        xpb[k * 256 + q] = xpv[k];
    }
    __syncthreads();
#pragma unroll
    for (int k = 0; k < 16; ++k) xpS[k][q] = xpv[k];
    __syncthreads();

    {
        const int kk = tid >> 4, c = tid & 15;
        float s = 0.f;
#pragma unroll
        for (int j = 0; j < 16; ++j) s += xpS[kk][c + 16 * j];
        for (int off = 8; off; off >>= 1) s += __shfl_down(s, off, 16);
        float mean = __shfl(s, 0, 16) * (1.f / 256.f);
        float vs = 0.f;
#pragma unroll
        for (int j = 0; j < 16; ++j) { float d = xpS[kk][c + 16 * j] - mean; vs += d * d; }
        for (int off = 8; off; off >>= 1) vs += __shfl_down(vs, off, 16);
        float rstd = rsqrtf(__shfl(vs, 0, 16) * (1.f / 256.f) + LN_EPS);
        if (c == 0) { mrS[kk][0] = mean; mrS[kk][1] = rstd; }
    }
    __syncthreads();
    ushort_t* hb = h + (size_t)b * 4096;
    const float g2q = g2[q], b2q = b2[q];
#pragma unroll
    for (int k = 0; k < 16; ++k) {
        float m = mrS[k][0], r = mrS[k][1];
        hb[k * 256 + q] = f2bf((xpS[k][q] - m) * r * g2q + b2q);
    }
}

// K3: F1g = gelu(h @ Wf1 + bf1), 128x128, grid (128,8)
__global__ __launch_bounds__(256) void k3_gemm(const ushort_t* __restrict__ h,
                                               const ushort_t* __restrict__ Wf1T,
                                               const float* __restrict__ bf1,
                                               ushort_t* __restrict__ F1g) {
    __shared__ ushort_t As[128][32];
    __shared__ ushort_t Bs[128][32];
    const int tid = threadIdx.x;
    const int m0 = blockIdx.x * 128, n0 = blockIdx.y * 128;
    f32x4 acc[4][4] = {};
    gemm128(h, Wf1T, 256, m0, n0, acc, As, Bs);
    const int wave = tid >> 6, lane = tid & 63, lq = lane >> 4, lr = lane & 15;
    const int wm = wave >> 1, wn = wave & 1;
#pragma unroll
    for (int i = 0; i < 4; ++i)
#pragma unroll
        for (int j = 0; j < 4; ++j) {
            int n = n0 + wn * 64 + j * 16 + lr;
            float bn = bf1[n];
#pragma unroll
            for (int v = 0; v < 4; ++v) {
                int rg = m0 + wm * 64 + i * 16 + lq * 4 + v;
                float u = acc[i][j][v] + bn;
                float gl = 0.5f * u * (1.f + erff(u * 0.70710678118f));
                F1g[(size_t)rg * 1024 + n] = f2bf(gl);
            }
        }
}

// K4: out = xp + F1g @ Wf2 + bf2, 64x128, grid (256,2)
__global__ __launch_bounds__(256) void k4_gemm(const ushort_t* __restrict__ F1g,
                                               const ushort_t* __restrict__ Wf2T,
                                               const float* __restrict__ bf2,
                                               const float* __restrict__ xp,
                                               float* __restrict__ out) {
    __shared__ ushort_t As[64][32];
    __shared__ ushort_t Bs[128][32];
    const int tid = threadIdx.x;
    const int m0 = blockIdx.x * 64, n0 = blockIdx.y * 128;
    f32x4 acc[2][4] = {};
    gemm64(F1g, Wf2T, 1024, m0, n0, acc, As, Bs);
    const int wave = tid >> 6, lane = tid & 63, lq = lane >> 4, lr = lane & 15;
    const int wm = wave >> 1, wn = wave & 1;
#pragma unroll
    for (int i = 0; i < 2; ++i)
#pragma unroll
        for (int j = 0; j < 4; ++j) {
            int n = n0 + wn * 64 + j * 16 + lr;
            float bn = bf2[n];
#pragma unroll
            for (int v = 0; v < 4; ++v) {
                size_t idx = (size_t)(m0 + wm * 32 + i * 16 + lq * 4 + v) * 256 + n;
                out[idx] = xp[idx] + acc[i][j][v] + bn;
            }
        }
}

extern "C" void kernel_launch(void* const* d_in, const int* in_sizes, int n_in,
                              void* d_out, int out_size, void* d_ws, size_t ws_size,
                              hipStream_t stream) {
    const float* x = (const float*)d_in[0];
    const float* mask = (const float*)d_in[1];
    const float* Wg = (const float*)d_in[2];
    const float* bg = (const float*)d_in[3];
    const float* ls = (const float*)d_in[4];
    const float* Wv = (const float*)d_in[5];
    const float* bv = (const float*)d_in[6];
    const float* We = (const float*)d_in[7];
    const float* be = (const float*)d_in[8];
    const float* Wo = (const float*)d_in[9];
    const float* bo = (const float*)d_in[10];
    const float* g1 = (const float*)d_in[11];
    const float* b1 = (const float*)d_in[12];
    const float* g2 = (const float*)d_in[13];
    const float* b2 = (const float*)d_in[14];
    const float* Wf1 = (const float*)d_in[15];
    const float* bf1 = (const float*)d_in[16];
    const float* Wf2 = (const float*)d_in[17];
    const float* bf2 = (const float*)d_in[18];
    float* out = (float*)d_out;

    char* ws = (char*)d_ws;
    ushort_t* Y = (ushort_t*)(ws);                      // 50,331,648
    ushort_t* F1g = (ushort_t*)(ws);                    // 33,554,432 (alias: Y dead after kZ)
    ushort_t* WkT = (ushort_t*)(ws + 50331648);         //    786,432
    ushort_t* Wf1T = (ushort_t*)(ws + 51118080);        //    524,288
    ushort_t* Wf2T = (ushort_t*)(ws + 51642368);        //    524,288
    float* cvpart = (float*)(ws + 52166656);            //      3,072
    float* beWo = (float*)(ws + 52169728);              //      3,072
    float* gbuf = (float*)(ws + 52172800);              //    196,608
    float* xp = (float*)(ws + 52369408);                // 16,777,216
    ushort_t* h = (ushort_t*)(ws + 69146624);           //  8,388,608
    ushort_t* xnbuf = (ushort_t*)(ws + 77535232);       //  8,388,608
    float* Mbuf = (float*)(ws + 85923840);              //  6,291,456  -> end 92,215,296

    kprep<<<dim3(518), dim3(256), 0, stream>>>(Wv, We, Wo, bv, be, Wf1, Wf2,
                                               WkT, Wf1T, Wf2T, cvpart, beWo);
    kLN1G<<<dim3(1024), dim3(256), 0, stream>>>(x, mask, Wg, bg, ls, g1, b1,
                                                xnbuf, Mbuf, gbuf);
    kY_gemm<<<dim3(128, 12), dim3(256), 0, stream>>>(xnbuf, WkT, Y);
    kZ_apply<<<dim3(1024), dim3(256), 0, stream>>>(Y, Mbuf, x, bo, cvpart, beWo, gbuf, g2, b2, xp, h);
    k3_gemm<<<dim3(128, 8), dim3(256), 0, stream>>>(h, Wf1T, bf1, F1g);
    k4_gemm<<<dim3(256, 2), dim3(256), 0, stream>>>(F1g, Wf2T, bf2, xp, out);
}